// Round 5
// baseline (286.030 us; speedup 1.0000x reference)
//
#include <hip/hip_runtime.h>
#include <math.h>

#define NN 8192
#define DD 14
#define DP 16
#define FF 2048
#define HID 256
#define LN_EPS 1e-5f
#define QSCALE (1.4426950408889634f / 3.7416573867739413f)  // log2(e)/sqrt(14)

typedef short bf16x8 __attribute__((ext_vector_type(8)));
typedef float f32x4 __attribute__((ext_vector_type(4)));

#define LOAD16(dst, srcp) { \
  const float4* _p = (const float4*)(srcp); \
  float4 _a = _p[0], _b = _p[1], _c = _p[2], _d = _p[3]; \
  dst[0]=_a.x; dst[1]=_a.y; dst[2]=_a.z; dst[3]=_a.w; \
  dst[4]=_b.x; dst[5]=_b.y; dst[6]=_b.z; dst[7]=_b.w; \
  dst[8]=_c.x; dst[9]=_c.y; dst[10]=_c.z; dst[11]=_c.w; \
  dst[12]=_d.x; dst[13]=_d.y; dst[14]=_d.z; dst[15]=_d.w; }

#define STORE16(dstp, src) { \
  float4* _p = (float4*)(dstp); \
  _p[0] = make_float4(src[0], src[1], src[2], src[3]); \
  _p[1] = make_float4(src[4], src[5], src[6], src[7]); \
  _p[2] = make_float4(src[8], src[9], src[10], src[11]); \
  _p[3] = make_float4(src[12], src[13], src[14], src[15]); }

static __device__ __forceinline__ float fast_exp2(float x) {
#if __has_builtin(__builtin_amdgcn_exp2f)
  return __builtin_amdgcn_exp2f(x);
#else
  return exp2f(x);
#endif
}

static __device__ __forceinline__ unsigned short bf_hi(float x) {
  return (unsigned short)(__float_as_uint(x) >> 16);
}
static __device__ __forceinline__ float bf_hi_f(float x) {
  return __uint_as_float(__float_as_uint(x) & 0xffff0000u);
}

// ---- repack 8 floats -> bf16 hi/lo fragments ----
static __device__ __forceinline__ void split8(const float* pv, bf16x8* ph, bf16x8* pl) {
  #pragma unroll
  for (int i = 0; i < 8; i++) {
    unsigned int u = __float_as_uint(pv[i]);
    (*ph)[i] = (short)(u >> 16);
    float rr = pv[i] - __uint_as_float(u & 0xffff0000u);
    (*pl)[i] = (short)(__float_as_uint(rr) >> 16);
  }
}

// ---- shared helper: compute qkv for row r from hr[16], store packed operands ----
static __device__ __forceinline__ void qkv_compute_store(
    int r, const float* hr, const float* __restrict__ wqkv,
    const float* __restrict__ bqkv, unsigned int* __restrict__ Qpack,
    unsigned int* __restrict__ KB1, unsigned int* __restrict__ KB2,
    unsigned short* __restrict__ VhiT, unsigned short* __restrict__ VloT) {
  float q[14], k[14], v[14];
  #pragma unroll 6
  for (int c = 0; c < 42; c++) {
    const float* w = wqkv + c * 14;
    float s = bqkv[c];
    #pragma unroll
    for (int d = 0; d < 14; d++) s = fmaf(hr[d], w[d], s);
    if (c < 14)       q[c] = s * QSCALE;
    else if (c < 28)  k[c - 14] = s;
    else              v[c - 28] = s;
  }
  unsigned int qp[16], k1[16], k2[16];
  unsigned short qh[14], ql[14], kh[14], kl[14];
  #pragma unroll
  for (int d = 0; d < 14; d++) {
    qh[d] = bf_hi(q[d]);
    ql[d] = bf_hi(q[d] - bf_hi_f(q[d]));
    kh[d] = bf_hi(k[d]);
    kl[d] = bf_hi(k[d] - bf_hi_f(k[d]));
  }
  #pragma unroll
  for (int i = 0; i < 7; i++) {
    qp[i]     = (unsigned int)qh[2*i] | ((unsigned int)qh[2*i+1] << 16);
    qp[8 + i] = (unsigned int)ql[2*i] | ((unsigned int)ql[2*i+1] << 16);
    k1[i]     = (unsigned int)kh[2*i] | ((unsigned int)kh[2*i+1] << 16);
    k1[8 + i] = k1[i];
    k2[i]     = (unsigned int)kl[2*i] | ((unsigned int)kl[2*i+1] << 16);
    k2[8 + i] = k2[i];
  }
  qp[7] = 0; qp[15] = 0; k1[7] = 0; k1[15] = 0; k2[7] = 0; k2[15] = 0;
  uint4* Qp4 = (uint4*)(Qpack + (size_t)r * 16);
  uint4* K14 = (uint4*)(KB1 + (size_t)r * 16);
  uint4* K24 = (uint4*)(KB2 + (size_t)r * 16);
  #pragma unroll
  for (int i = 0; i < 4; i++) {
    Qp4[i] = make_uint4(qp[4*i], qp[4*i+1], qp[4*i+2], qp[4*i+3]);
    K14[i] = make_uint4(k1[4*i], k1[4*i+1], k1[4*i+2], k1[4*i+3]);
    K24[i] = make_uint4(k2[4*i], k2[4*i+1], k2[4*i+2], k2[4*i+3]);
  }
  #pragma unroll
  for (int d = 0; d < 14; d++) {
    VhiT[(size_t)d * NN + r] = bf_hi(v[d]);
    VloT[(size_t)d * NN + r] = bf_hi(v[d] - bf_hi_f(v[d]));
  }
  VhiT[(size_t)14 * NN + r] = 0x3F80;  // ones column = softmax denom
  VhiT[(size_t)15 * NN + r] = 0;
  VloT[(size_t)14 * NN + r] = 0;
  VloT[(size_t)15 * NN + r] = 0;
}

// ---- shared helper: A-operand pack of 14-dim vector (hi|lo) ----
static __device__ __forceinline__ void store_apack(unsigned int* dst, const float* o) {
  unsigned int qp[16];
  unsigned short hh[14], ll[14];
  #pragma unroll
  for (int d = 0; d < 14; d++) {
    hh[d] = bf_hi(o[d]);
    ll[d] = bf_hi(o[d] - bf_hi_f(o[d]));
  }
  #pragma unroll
  for (int i = 0; i < 7; i++) {
    qp[i]     = (unsigned int)hh[2*i] | ((unsigned int)hh[2*i+1] << 16);
    qp[8 + i] = (unsigned int)ll[2*i] | ((unsigned int)ll[2*i+1] << 16);
  }
  qp[7] = 0; qp[15] = 0;
  uint4* d4 = (uint4*)dst;
  #pragma unroll
  for (int i = 0; i < 4; i++)
    d4[i] = make_uint4(qp[4*i], qp[4*i+1], qp[4*i+2], qp[4*i+3]);
}

// ---- combine + LN (out-proj variant) ----
static __device__ __forceinline__ void combine_ln1(
    const float* srow, const float* hr, const float* __restrict__ wo,
    const float* __restrict__ bo, const float* __restrict__ g,
    const float* __restrict__ b, float* o) {
  float L = srow[14];
  float inv = 1.f / L;
  float a[14];
  #pragma unroll
  for (int d = 0; d < 14; d++) a[d] = srow[d] * inv;
  float xx[14];
  #pragma unroll
  for (int i = 0; i < 14; i++) {
    float s = bo[i];
    #pragma unroll
    for (int d = 0; d < 14; d++) s = fmaf(wo[i * 14 + d], a[d], s);
    xx[i] = hr[i] + s;
  }
  float mu = 0.f;
  #pragma unroll
  for (int i = 0; i < 14; i++) mu += xx[i];
  mu *= (1.f / 14.f);
  float var = 0.f;
  #pragma unroll
  for (int i = 0; i < 14; i++) { float tt = xx[i] - mu; var = fmaf(tt, tt, var); }
  var *= (1.f / 14.f);
  float rs = rsqrtf(var + LN_EPS);
  #pragma unroll
  for (int i = 0; i < 14; i++) o[i] = fmaf((xx[i] - mu) * rs, g[i], b[i]);
  o[14] = 0.f; o[15] = 0.f;
}

// ======================================================================
// K1: weight packs (fc3/fc4/ffn) + layer-0 qkv from x  (unchanged, proven)
// ======================================================================
__global__ void pack_all(const float* __restrict__ w3, const float* __restrict__ w4,
                         const float* __restrict__ ffw1, const float* __restrict__ ffw2,
                         const float* __restrict__ x, const float* __restrict__ wqkv,
                         const float* __restrict__ bqkv, float* __restrict__ h,
                         unsigned int* __restrict__ Qpack,
                         unsigned int* __restrict__ KB1, unsigned int* __restrict__ KB2,
                         unsigned short* __restrict__ VhiT, unsigned short* __restrict__ VloT,
                         unsigned short* __restrict__ B3h, unsigned short* __restrict__ B3l,
                         unsigned short* __restrict__ B4h, unsigned short* __restrict__ B4l,
                         unsigned int* __restrict__ W1B1, unsigned int* __restrict__ W1B2,
                         unsigned short* __restrict__ W2h, unsigned short* __restrict__ W2l) {
  const int blk = blockIdx.x, tid = threadIdx.x;
  if (blk < 32) {
    int t = blk * 256 + tid;
    int lane = t & 63, ks = (t >> 6) & 7, nt = t >> 9;
    int n = nt * 16 + (lane & 15);
    int k0 = ks * 32 + (lane >> 4) * 8;
    unsigned int h4[4], l4[4];
    #pragma unroll
    for (int jj = 0; jj < 4; jj++) {
      unsigned short h2[2], l2[2];
      #pragma unroll
      for (int e = 0; e < 2; e++) {
        float v = w4[(size_t)n * 256 + k0 + jj * 2 + e];
        h2[e] = bf_hi(v);
        l2[e] = bf_hi(v - bf_hi_f(v));
      }
      h4[jj] = (unsigned int)h2[0] | ((unsigned int)h2[1] << 16);
      l4[jj] = (unsigned int)l2[0] | ((unsigned int)l2[1] << 16);
    }
    ((uint4*)B4h)[t] = make_uint4(h4[0], h4[1], h4[2], h4[3]);
    ((uint4*)B4l)[t] = make_uint4(l4[0], l4[1], l4[2], l4[3]);
    if (ks < 2) {
      int fi = (nt * 2 + ks) * 64 + lane;
      #pragma unroll
      for (int jj = 0; jj < 4; jj++) {
        unsigned short h2[2], l2[2];
        #pragma unroll
        for (int e = 0; e < 2; e++) {
          int k = k0 + jj * 2 + e;
          float v = (k < 51) ? w3[(size_t)n * 51 + k] : 0.f;
          h2[e] = bf_hi(v);
          l2[e] = bf_hi(v - bf_hi_f(v));
        }
        h4[jj] = (unsigned int)h2[0] | ((unsigned int)h2[1] << 16);
        l4[jj] = (unsigned int)l2[0] | ((unsigned int)l2[1] << 16);
      }
      ((uint4*)B3h)[fi] = make_uint4(h4[0], h4[1], h4[2], h4[3]);
      ((uint4*)B3l)[fi] = make_uint4(l4[0], l4[1], l4[2], l4[3]);
    }
  } else if (blk < 48) {
    int t = (blk - 32) * 256 + tid;
    int l = t >> 11, j = t & 2047;
    const float* wrow = ffw1 + ((size_t)l * FF + j) * 14;
    unsigned int k1[16], k2[16];
    unsigned short kh[14], kl[14];
    #pragma unroll
    for (int d = 0; d < 14; d++) {
      float v = wrow[d];
      kh[d] = bf_hi(v);
      kl[d] = bf_hi(v - bf_hi_f(v));
    }
    #pragma unroll
    for (int i = 0; i < 7; i++) {
      k1[i] = (unsigned int)kh[2*i] | ((unsigned int)kh[2*i+1] << 16);
      k1[8 + i] = k1[i];
      k2[i] = (unsigned int)kl[2*i] | ((unsigned int)kl[2*i+1] << 16);
      k2[8 + i] = k2[i];
    }
    k1[7] = 0; k1[15] = 0; k2[7] = 0; k2[15] = 0;
    uint4* d1 = (uint4*)(W1B1 + (size_t)t * 16);
    uint4* d2 = (uint4*)(W1B2 + (size_t)t * 16);
    #pragma unroll
    for (int i = 0; i < 4; i++) {
      d1[i] = make_uint4(k1[4*i], k1[4*i+1], k1[4*i+2], k1[4*i+3]);
      d2[i] = make_uint4(k2[4*i], k2[4*i+1], k2[4*i+2], k2[4*i+3]);
    }
  } else if (blk < 64) {
    int t = (blk - 48) * 256 + tid;
    int l = t >> 11, j = t & 2047;
    #pragma unroll
    for (int d = 0; d < 16; d++) {
      float v = (d < 14) ? ffw2[((size_t)l * 14 + d) * FF + j] : 0.f;
      W2h[((size_t)l * 16 + d) * FF + j] = bf_hi(v);
      W2l[((size_t)l * 16 + d) * FF + j] = bf_hi(v - bf_hi_f(v));
    }
  } else {
    int r = (blk - 64) * 256 + tid;
    float hr[16];
    #pragma unroll
    for (int d = 0; d < 14; d++) hr[d] = x[(size_t)r * 14 + d];
    hr[14] = 0.f; hr[15] = 0.f;
    STORE16(h + (size_t)r * DP, hr);
    qkv_compute_store(r, hr, wqkv, bqkv, Qpack, KB1, KB2, VhiT, VloT);
  }
}

// ======================================================================
// Pipelined 16-row attention core: wave covers 1024 keys in 32-key
// chunks; LDS reads of P(c-1) issued before writes of P(c) (per-wave DS
// order guarantees old data), so S-MFMA+exp hide the read latency.
// ======================================================================
static __device__ __forceinline__ void attn_core16(
    const bf16x8* __restrict__ Qp, const bf16x8* __restrict__ B1,
    const bf16x8* __restrict__ B2, const bf16x8* __restrict__ Vh,
    const bf16x8* __restrict__ Vl, int qbase, int wave, int lo4, int hi4,
    float (*Pl)[36], f32x4* o0) {
  const f32x4 zero = {0.f, 0.f, 0.f, 0.f};
  bf16x8 aQ0 = Qp[(size_t)(qbase + lo4) * 4 + hi4];
  f32x4 acc0 = zero;
  const int kstart = wave * 1024;
  float4 ra0, ra1;
  const float4* p0 = (const float4*)&Pl[lo4][hi4 * 8];

  for (int c = 0; c < 32; c++) {
    const int kb = kstart + c * 32;
    if (c > 0) {            // issue reads of P(c-1) early
      ra0 = p0[0]; ra1 = p0[1];
      __asm__ volatile("" ::: "memory");   // keep reads above the writes below
    }
    bf16x8 b1g0 = B1[(size_t)(kb + lo4) * 4 + hi4];
    bf16x8 b2g0 = B2[(size_t)(kb + lo4) * 4 + hi4];
    bf16x8 b1g1 = B1[(size_t)(kb + 16 + lo4) * 4 + hi4];
    bf16x8 b2g1 = B2[(size_t)(kb + 16 + lo4) * 4 + hi4];

    f32x4 s00 = __builtin_amdgcn_mfma_f32_16x16x32_bf16(aQ0, b1g0, zero, 0, 0, 0);
    f32x4 s01 = __builtin_amdgcn_mfma_f32_16x16x32_bf16(aQ0, b1g1, zero, 0, 0, 0);
    s00 = __builtin_amdgcn_mfma_f32_16x16x32_bf16(aQ0, b2g0, s00, 0, 0, 0);
    s01 = __builtin_amdgcn_mfma_f32_16x16x32_bf16(aQ0, b2g1, s01, 0, 0, 0);
    #pragma unroll
    for (int reg = 0; reg < 4; reg++) {
      Pl[hi4 * 4 + reg][lo4]      = fast_exp2(s00[reg]);
      Pl[hi4 * 4 + reg][16 + lo4] = fast_exp2(s01[reg]);
    }
    if (c > 0) {            // PV of chunk c-1
      const int kbp = kb - 32;
      bf16x8 vhp = Vh[(size_t)lo4 * 1024 + (kbp >> 3) + hi4];
      bf16x8 vlp = Vl[(size_t)lo4 * 1024 + (kbp >> 3) + hi4];
      float pv0[8] = {ra0.x, ra0.y, ra0.z, ra0.w, ra1.x, ra1.y, ra1.z, ra1.w};
      bf16x8 ph0, pl0;
      split8(pv0, &ph0, &pl0);
      acc0 = __builtin_amdgcn_mfma_f32_16x16x32_bf16(ph0, vhp, acc0, 0, 0, 0);
      acc0 = __builtin_amdgcn_mfma_f32_16x16x32_bf16(pl0, vhp, acc0, 0, 0, 0);
      acc0 = __builtin_amdgcn_mfma_f32_16x16x32_bf16(ph0, vlp, acc0, 0, 0, 0);
    }
  }
  // epilogue: PV of chunk 31
  {
    const int kbp = kstart + 31 * 32;
    bf16x8 vhp = Vh[(size_t)lo4 * 1024 + (kbp >> 3) + hi4];
    bf16x8 vlp = Vl[(size_t)lo4 * 1024 + (kbp >> 3) + hi4];
    float4 a0 = p0[0], a1 = p0[1];
    float pv0[8] = {a0.x, a0.y, a0.z, a0.w, a1.x, a1.y, a1.z, a1.w};
    bf16x8 ph0, pl0;
    split8(pv0, &ph0, &pl0);
    acc0 = __builtin_amdgcn_mfma_f32_16x16x32_bf16(ph0, vhp, acc0, 0, 0, 0);
    acc0 = __builtin_amdgcn_mfma_f32_16x16x32_bf16(pl0, vhp, acc0, 0, 0, 0);
    acc0 = __builtin_amdgcn_mfma_f32_16x16x32_bf16(ph0, vlp, acc0, 0, 0, 0);
  }
  *o0 = acc0;
}

// ======================================================================
// Pipelined 16-row FFN core: wave covers 256 neurons in 8 chunks of 32.
// ======================================================================
static __device__ __forceinline__ void ffn_core16(
    bf16x8 aH0, const bf16x8* __restrict__ B1, const bf16x8* __restrict__ B2,
    const bf16x8* __restrict__ Vh, const bf16x8* __restrict__ Vl,
    const float* __restrict__ b1, int jstart, int lo4, int hi4,
    float (*Pl)[36], f32x4* o0) {
  const f32x4 zero = {0.f, 0.f, 0.f, 0.f};
  f32x4 acc0 = zero;
  float4 ra0, ra1;
  const float4* p0 = (const float4*)&Pl[lo4][hi4 * 8];

  for (int c = 0; c < 8; c++) {
    const int jb = jstart + c * 32;
    if (c > 0) {
      ra0 = p0[0]; ra1 = p0[1];
      __asm__ volatile("" ::: "memory");
    }
    bf16x8 b1g0 = B1[(size_t)(jb + lo4) * 4 + hi4];
    bf16x8 b2g0 = B2[(size_t)(jb + lo4) * 4 + hi4];
    bf16x8 b1g1 = B1[(size_t)(jb + 16 + lo4) * 4 + hi4];
    bf16x8 b2g1 = B2[(size_t)(jb + 16 + lo4) * 4 + hi4];
    float bb0 = b1[jb + lo4];
    float bb1 = b1[jb + 16 + lo4];

    f32x4 s00 = __builtin_amdgcn_mfma_f32_16x16x32_bf16(aH0, b1g0, zero, 0, 0, 0);
    f32x4 s01 = __builtin_amdgcn_mfma_f32_16x16x32_bf16(aH0, b1g1, zero, 0, 0, 0);
    s00 = __builtin_amdgcn_mfma_f32_16x16x32_bf16(aH0, b2g0, s00, 0, 0, 0);
    s01 = __builtin_amdgcn_mfma_f32_16x16x32_bf16(aH0, b2g1, s01, 0, 0, 0);
    #pragma unroll
    for (int reg = 0; reg < 4; reg++) {
      Pl[hi4 * 4 + reg][lo4]      = fmaxf(s00[reg] + bb0, 0.f);
      Pl[hi4 * 4 + reg][16 + lo4] = fmaxf(s01[reg] + bb1, 0.f);
    }
    if (c > 0) {
      const int jbp = jb - 32;
      bf16x8 vhp = Vh[(size_t)lo4 * 256 + (jbp >> 3) + hi4];
      bf16x8 vlp = Vl[(size_t)lo4 * 256 + (jbp >> 3) + hi4];
      float pv0[8] = {ra0.x, ra0.y, ra0.z, ra0.w, ra1.x, ra1.y, ra1.z, ra1.w};
      bf16x8 th0, tl0;
      split8(pv0, &th0, &tl0);
      acc0 = __builtin_amdgcn_mfma_f32_16x16x32_bf16(th0, vhp, acc0, 0, 0, 0);
      acc0 = __builtin_amdgcn_mfma_f32_16x16x32_bf16(tl0, vhp, acc0, 0, 0, 0);
      acc0 = __builtin_amdgcn_mfma_f32_16x16x32_bf16(th0, vlp, acc0, 0, 0, 0);
    }
  }
  {
    const int jbp = jstart + 7 * 32;
    bf16x8 vhp = Vh[(size_t)lo4 * 256 + (jbp >> 3) + hi4];
    bf16x8 vlp = Vl[(size_t)lo4 * 256 + (jbp >> 3) + hi4];
    float4 a0 = p0[0], a1 = p0[1];
    float pv0[8] = {a0.x, a0.y, a0.z, a0.w, a1.x, a1.y, a1.z, a1.w};
    bf16x8 th0, tl0;
    split8(pv0, &th0, &tl0);
    acc0 = __builtin_amdgcn_mfma_f32_16x16x32_bf16(th0, vhp, acc0, 0, 0, 0);
    acc0 = __builtin_amdgcn_mfma_f32_16x16x32_bf16(tl0, vhp, acc0, 0, 0, 0);
    acc0 = __builtin_amdgcn_mfma_f32_16x16x32_bf16(th0, vlp, acc0, 0, 0, 0);
  }
  *o0 = acc0;
}

// LDS layout (bytes), 16-row blocks:
//  main : Pl    8 x [16][36] f32   0..18432
//         sacc  [8][16][16] f32    18432..26624
//         hrow  [16][16] f32       26624..27648
//         Hl    [16][16] u32       27648..28672
//  tail : Ah [16][72] 0..2304 | Al 2304..4608 | R1h 4608..13056 |
//         R1l 13056..21504 | sred [8][16][16] 21504..29696
//  szf  : [16] f32 at 29696 (shared by both layouts)
#define SMEM_BYTES 29760

// ======================================================================
// K2: layer 0 (16 rows/block, 512 blocks) = attn + LN1 + ffn + LN2 +
// layer-1 qkv pack into separate buffers.
// ======================================================================
__global__ __launch_bounds__(512, 4) void layer0_fused(
    const unsigned int* __restrict__ Qpack, const unsigned int* __restrict__ KB1,
    const unsigned int* __restrict__ KB2, const unsigned short* __restrict__ VhiT,
    const unsigned short* __restrict__ VloT, float* __restrict__ h,
    const float* __restrict__ wo, const float* __restrict__ bo,
    const float* __restrict__ g1, const float* __restrict__ b1n,
    const unsigned int* __restrict__ W1B1, const unsigned int* __restrict__ W1B2,
    const unsigned short* __restrict__ W2h, const unsigned short* __restrict__ W2l,
    const float* __restrict__ fb1, const float* __restrict__ fb2,
    const float* __restrict__ g2, const float* __restrict__ b2n,
    const float* __restrict__ wqkv1, const float* __restrict__ bqkv1,
    unsigned int* __restrict__ Qpack1, unsigned int* __restrict__ KB1_1,
    unsigned int* __restrict__ KB2_1, unsigned short* __restrict__ VhiT1,
    unsigned short* __restrict__ VloT1) {
  __shared__ alignas(16) char smem[SMEM_BYTES];
  const int tid = threadIdx.x;
  const int wave = tid >> 6;
  const int lane = tid & 63;
  const int lo4 = lane & 15;
  const int hi4 = lane >> 4;
  const int qbase = blockIdx.x * 16;

  float (*Pl)[36] = (float(*)[36])(smem + wave * 2304);
  float (*sacc)[16][16] = (float(*)[16][16])(smem + 18432);
  float (*hrow)[16] = (float(*)[16])(smem + 26624);
  unsigned int (*Hl)[16] = (unsigned int(*)[16])(smem + 27648);

  // ---- phase A: attention ----
  f32x4 a0;
  attn_core16((const bf16x8*)Qpack, (const bf16x8*)KB1, (const bf16x8*)KB2,
              (const bf16x8*)VhiT, (const bf16x8*)VloT, qbase, wave, lo4, hi4,
              Pl, &a0);
  #pragma unroll
  for (int reg = 0; reg < 4; reg++)
    sacc[wave][hi4 * 4 + reg][lo4] = a0[reg];
  __syncthreads();
  if (tid < 256) {
    int qq = tid >> 4, col = tid & 15;
    float v = 0.f;
    #pragma unroll
    for (int w = 0; w < 8; w++) v += sacc[w][qq][col];
    sacc[0][qq][col] = v;
  }
  __syncthreads();
  if (tid < 16) {
    int r = qbase + tid;
    float hr[16];
    LOAD16(hr, h + (size_t)r * DP);
    float o[16];
    combine_ln1(&sacc[0][tid][0], hr, wo, bo, g1, b1n, o);
    #pragma unroll
    for (int i = 0; i < 16; i++) hrow[tid][i] = o[i];
    store_apack(&Hl[tid][0], o);
  }
  __syncthreads();

  // ---- phase B: FFN ----
  bf16x8 aH0 = *(const bf16x8*)&Hl[lo4][hi4 * 4];
  f32x4 f0;
  ffn_core16(aH0, (const bf16x8*)W1B1, (const bf16x8*)W1B2,
             (const bf16x8*)W2h, (const bf16x8*)W2l, fb1, wave * 256,
             lo4, hi4, Pl, &f0);
  #pragma unroll
  for (int reg = 0; reg < 4; reg++)
    sacc[wave][hi4 * 4 + reg][lo4] = f0[reg];
  __syncthreads();
  if (tid < 256) {
    int qq = tid >> 4, col = tid & 15;
    float v = 0.f;
    #pragma unroll
    for (int w = 0; w < 8; w++) v += sacc[w][qq][col];
    sacc[0][qq][col] = v;
  }
  __syncthreads();
  if (tid < 16) {
    int r = qbase + tid;
    float xx[14];
    #pragma unroll
    for (int i = 0; i < 14; i++) xx[i] = hrow[tid][i] + sacc[0][tid][i] + fb2[i];
    float mu = 0.f;
    #pragma unroll
    for (int i = 0; i < 14; i++) mu += xx[i];
    mu *= (1.f / 14.f);
    float var = 0.f;
    #pragma unroll
    for (int i = 0; i < 14; i++) { float tt = xx[i] - mu; var = fmaf(tt, tt, var); }
    var *= (1.f / 14.f);
    float rs = rsqrtf(var + LN_EPS);
    float o[16];
    #pragma unroll
    for (int i = 0; i < 14; i++) o[i] = fmaf((xx[i] - mu) * rs, g2[i], b2n[i]);
    o[14] = 0.f; o[15] = 0.f;
    STORE16(h + (size_t)r * DP, o);
    qkv_compute_store(r, o, wqkv1, bqkv1, Qpack1, KB1_1, KB2_1, VhiT1, VloT1);
  }
}

// ======================================================================
// K3: layer 1 (16 rows/block, 512 blocks) = attn + LN1 + ffn + LN2 +
// size head + regression tail (8 waves x 2 neuron-tiles).
// ======================================================================
__global__ __launch_bounds__(512, 4) void layer1_tail(
    const unsigned int* __restrict__ Qpack, const unsigned int* __restrict__ KB1,
    const unsigned int* __restrict__ KB2, const unsigned short* __restrict__ VhiT,
    const unsigned short* __restrict__ VloT, const float* __restrict__ h,
    const float* __restrict__ wo, const float* __restrict__ bo,
    const float* __restrict__ g1, const float* __restrict__ b1n,
    const unsigned int* __restrict__ W1B1, const unsigned int* __restrict__ W1B2,
    const unsigned short* __restrict__ W2h, const unsigned short* __restrict__ W2l,
    const float* __restrict__ fb1, const float* __restrict__ fb2,
    const float* __restrict__ g2, const float* __restrict__ b2n,
    const float* __restrict__ fc1w, const float* __restrict__ fc1b,
    const float* __restrict__ fc2w, const float* __restrict__ fc2b,
    const float* __restrict__ x, const float* __restrict__ y,
    const unsigned short* __restrict__ B3h, const unsigned short* __restrict__ B3l,
    const float* __restrict__ b3,
    const unsigned short* __restrict__ B4h, const unsigned short* __restrict__ B4l,
    const float* __restrict__ b4,
    const float* __restrict__ w5, const float* __restrict__ b5,
    float* __restrict__ out, float* __restrict__ outr) {
  __shared__ alignas(16) char smem[SMEM_BYTES];
  const int tid = threadIdx.x;
  const int wave = tid >> 6;
  const int lane = tid & 63;
  const int lo4 = lane & 15;
  const int hi4 = lane >> 4;
  const int qbase = blockIdx.x * 16;
  const f32x4 zero = {0.f, 0.f, 0.f, 0.f};

  float (*Pl)[36] = (float(*)[36])(smem + wave * 2304);
  float (*sacc)[16][16] = (float(*)[16][16])(smem + 18432);
  float (*hrow)[16] = (float(*)[16])(smem + 26624);
  unsigned int (*Hl)[16] = (unsigned int(*)[16])(smem + 27648);
  float* szf = (float*)(smem + 29696);

  // ---- phase A: attention ----
  f32x4 a0;
  attn_core16((const bf16x8*)Qpack, (const bf16x8*)KB1, (const bf16x8*)KB2,
              (const bf16x8*)VhiT, (const bf16x8*)VloT, qbase, wave, lo4, hi4,
              Pl, &a0);
  #pragma unroll
  for (int reg = 0; reg < 4; reg++)
    sacc[wave][hi4 * 4 + reg][lo4] = a0[reg];
  __syncthreads();
  if (tid < 256) {
    int qq = tid >> 4, col = tid & 15;
    float v = 0.f;
    #pragma unroll
    for (int w = 0; w < 8; w++) v += sacc[w][qq][col];
    sacc[0][qq][col] = v;
  }
  __syncthreads();
  if (tid < 16) {
    int r = qbase + tid;
    float hr[16];
    LOAD16(hr, h + (size_t)r * DP);
    float o[16];
    combine_ln1(&sacc[0][tid][0], hr, wo, bo, g1, b1n, o);
    #pragma unroll
    for (int i = 0; i < 16; i++) hrow[tid][i] = o[i];
    store_apack(&Hl[tid][0], o);
  }
  __syncthreads();

  // ---- phase B: FFN + LN2 + size head ----
  bf16x8 aH0 = *(const bf16x8*)&Hl[lo4][hi4 * 4];
  f32x4 f0;
  ffn_core16(aH0, (const bf16x8*)W1B1, (const bf16x8*)W1B2,
             (const bf16x8*)W2h, (const bf16x8*)W2l, fb1, wave * 256,
             lo4, hi4, Pl, &f0);
  #pragma unroll
  for (int reg = 0; reg < 4; reg++)
    sacc[wave][hi4 * 4 + reg][lo4] = f0[reg];
  __syncthreads();
  if (tid < 256) {
    int qq = tid >> 4, col = tid & 15;
    float v = 0.f;
    #pragma unroll
    for (int w = 0; w < 8; w++) v += sacc[w][qq][col];
    sacc[0][qq][col] = v;
  }
  __syncthreads();
  if (tid < 16) {
    int r = qbase + tid;
    float xx[14];
    #pragma unroll
    for (int i = 0; i < 14; i++) xx[i] = hrow[tid][i] + sacc[0][tid][i] + fb2[i];
    float mu = 0.f;
    #pragma unroll
    for (int i = 0; i < 14; i++) mu += xx[i];
    mu *= (1.f / 14.f);
    float var = 0.f;
    #pragma unroll
    for (int i = 0; i < 14; i++) { float tt = xx[i] - mu; var = fmaf(tt, tt, var); }
    var *= (1.f / 14.f);
    float rs = rsqrtf(var + LN_EPS);
    float o[14];
    #pragma unroll
    for (int i = 0; i < 14; i++) o[i] = fmaf((xx[i] - mu) * rs, g2[i], b2n[i]);
    float s = fc2b[0];
    #pragma unroll
    for (int i = 0; i < 14; i++) {
      float tt = fc1b[i];
      #pragma unroll
      for (int d = 0; d < 14; d++) tt = fmaf(fc1w[i * 14 + d], o[d], tt);
      s = fmaf(tt, fc2w[i], s);
    }
    out[r] = s;
    int si = (int)s;  // trunc toward zero, matches astype(int32)
    szf[tid] = (float)si;
  }
  __syncthreads();

  // ---- phase C: regression head (8 waves x 2 neuron-tiles, 16 rows) ----
  unsigned short (*Ah)[72]  = (unsigned short(*)[72])(smem);
  unsigned short (*Al)[72]  = (unsigned short(*)[72])(smem + 2304);
  unsigned short (*R1h)[264] = (unsigned short(*)[264])(smem + 4608);
  unsigned short (*R1l)[264] = (unsigned short(*)[264])(smem + 13056);
  float (*sred)[16][16] = (float(*)[16][16])(smem + 21504);

  for (int idx = tid; idx < 16 * 64; idx += 512) {
    int m = idx >> 6, k = idx & 63;
    int r = qbase + m;
    float v = 0.f;
    if (k == 0)       v = szf[m];
    else if (k < 15)  v = x[(size_t)r * 14 + (k - 1)];
    else if (k < 51)  v = y[(size_t)r * 36 + (k - 15)];
    Ah[m][k] = bf_hi(v);
    Al[m][k] = bf_hi(v - bf_hi_f(v));
  }
  __syncthreads();

  f32x4 acc[2];
  #pragma unroll
  for (int nt = 0; nt < 2; nt++) acc[nt] = zero;
  #pragma unroll
  for (int ks = 0; ks < 2; ks++) {
    bf16x8 ah = *(const bf16x8*)&Ah[lo4][ks * 32 + hi4 * 8];
    bf16x8 al = *(const bf16x8*)&Al[lo4][ks * 32 + hi4 * 8];
    #pragma unroll
    for (int nt = 0; nt < 2; nt++) {
      int fi = ((wave * 2 + nt) * 2 + ks) * 64 + lane;
      bf16x8 bh = ((const bf16x8*)B3h)[fi];
      bf16x8 bl = ((const bf16x8*)B3l)[fi];
      acc[nt] = __builtin_amdgcn_mfma_f32_16x16x32_bf16(ah, bh, acc[nt], 0, 0, 0);
      acc[nt] = __builtin_amdgcn_mfma_f32_16x16x32_bf16(al, bh, acc[nt], 0, 0, 0);
      acc[nt] = __builtin_amdgcn_mfma_f32_16x16x32_bf16(ah, bl, acc[nt], 0, 0, 0);
    }
  }
  #pragma unroll
  for (int nt = 0; nt < 2; nt++) {
    int n = (wave * 2 + nt) * 16 + lo4;
    float bbv = b3[n];
    #pragma unroll
    for (int reg = 0; reg < 4; reg++) {
      int m = hi4 * 4 + reg;
      float v = fmaxf(acc[nt][reg] + bbv, 0.f);
      R1h[m][n] = bf_hi(v);
      R1l[m][n] = bf_hi(v - bf_hi_f(v));
    }
  }
  __syncthreads();

  #pragma unroll
  for (int nt = 0; nt < 2; nt++) acc[nt] = zero;
  #pragma unroll
  for (int ks = 0; ks < 8; ks++) {
    bf16x8 ah = *(const bf16x8*)&R1h[lo4][ks * 32 + hi4 * 8];
    bf16x8 al = *(const bf16x8*)&R1l[lo4][ks * 32 + hi4 * 8];
    #pragma unroll
    for (int nt = 0; nt < 2; nt++) {
      int fi = ((wave * 2 + nt) * 8 + ks) * 64 + lane;
      bf16x8 bh = ((const bf16x8*)B4h)[fi];
      bf16x8 bl = ((const bf16x8*)B4l)[fi];
      acc[nt] = __builtin_amdgcn_mfma_f32_16x16x32_bf16(ah, bh, acc[nt], 0, 0, 0);
      acc[nt] = __builtin_amdgcn_mfma_f32_16x16x32_bf16(al, bh, acc[nt], 0, 0, 0);
      acc[nt] = __builtin_amdgcn_mfma_f32_16x16x32_bf16(ah, bl, acc[nt], 0, 0, 0);
    }
  }
  float s4[4] = {0.f, 0.f, 0.f, 0.f};
  #pragma unroll
  for (int nt = 0; nt < 2; nt++) {
    int n = (wave * 2 + nt) * 16 + lo4;
    float bbv = b4[n], ww = w5[n];
    #pragma unroll
    for (int reg = 0; reg < 4; reg++)
      s4[reg] = fmaf(fmaxf(acc[nt][reg] + bbv, 0.f), ww, s4[reg]);
  }
  #pragma unroll
  for (int reg = 0; reg < 4; reg++) sred[wave][hi4 * 4 + reg][lo4] = s4[reg];
  __syncthreads();

  if (tid < 16) {
    float t = b5[0];
    #pragma unroll
    for (int w = 0; w < 8; w++) {
      const float4* p = (const float4*)&sred[w][tid][0];
      float4 q0 = p[0], q1 = p[1], q2 = p[2], q3 = p[3];
      t += ((q0.x + q0.y) + (q0.z + q0.w)) + ((q1.x + q1.y) + (q1.z + q1.w)) +
           ((q2.x + q2.y) + (q2.z + q2.w)) + ((q3.x + q3.y) + (q3.z + q3.w));
    }
    float sz = szf[tid];
    outr[qbase + tid] = (sz != 0.f) ? t : 0.f;
  }
}

extern "C" void kernel_launch(void* const* d_in, const int* in_sizes, int n_in,
                              void* d_out, int out_size, void* d_ws, size_t ws_size,
                              hipStream_t stream) {
  const float* x    = (const float*)d_in[0];
  const float* y    = (const float*)d_in[1];
  const float* wqkv = (const float*)d_in[2];
  const float* bqkv = (const float*)d_in[3];
  const float* wo   = (const float*)d_in[4];
  const float* bo   = (const float*)d_in[5];
  const float* ln1g = (const float*)d_in[6];
  const float* ln1b = (const float*)d_in[7];
  const float* ffw1 = (const float*)d_in[8];
  const float* ffb1 = (const float*)d_in[9];
  const float* ffw2 = (const float*)d_in[10];
  const float* ffb2 = (const float*)d_in[11];
  const float* ln2g = (const float*)d_in[12];
  const float* ln2b = (const float*)d_in[13];
  const float* fc1w = (const float*)d_in[14];
  const float* fc1b = (const float*)d_in[15];
  const float* fc2w = (const float*)d_in[16];
  const float* fc2b = (const float*)d_in[17];
  const float* fc3w = (const float*)d_in[18];
  const float* fc3b = (const float*)d_in[19];
  const float* fc4w = (const float*)d_in[20];
  const float* fc4b = (const float*)d_in[21];
  const float* fc5w = (const float*)d_in[22];
  const float* fc5b = (const float*)d_in[23];

  float* ws = (float*)d_ws;
  float*          h      = ws;                               // 131072 f
  unsigned int*   Qpack0 = (unsigned int*)(ws + 131072);
  unsigned int*   KB1_0  = (unsigned int*)(ws + 262144);
  unsigned int*   KB2_0  = (unsigned int*)(ws + 393216);
  unsigned short* VhiT0  = (unsigned short*)(ws + 524288);
  unsigned short* VloT0  = (unsigned short*)(ws + 589824);
  unsigned int*   Qpack1 = (unsigned int*)(ws + 786432);
  unsigned int*   KB1_1  = (unsigned int*)(ws + 917504);
  unsigned int*   KB2_1  = (unsigned int*)(ws + 1048576);
  unsigned short* VhiT1  = (unsigned short*)(ws + 1179648);
  unsigned short* VloT1  = (unsigned short*)(ws + 1245184);
  unsigned short* B3h    = (unsigned short*)(ws + 2891776);
  unsigned short* B3l    = (unsigned short*)(ws + 2899968);
  unsigned short* B4h    = (unsigned short*)(ws + 2908160);
  unsigned short* B4l    = (unsigned short*)(ws + 2940928);
  unsigned int*   W1B1   = (unsigned int*)(ws + 2973696);
  unsigned int*   W1B2   = (unsigned int*)(ws + 3039232);
  unsigned short* W2h    = (unsigned short*)(ws + 3104768);
  unsigned short* W2l    = (unsigned short*)(ws + 3137536);

  float* out = (float*)d_out;

  pack_all<<<96, 256, 0, stream>>>(fc3w, fc4w, ffw1, ffw2, x, wqkv, bqkv, h,
                                   Qpack0, KB1_0, KB2_0, VhiT0, VloT0,
                                   B3h, B3l, B4h, B4l, W1B1, W1B2, W2h, W2l);

  layer0_fused<<<512, 512, 0, stream>>>(
      Qpack0, KB1_0, KB2_0, VhiT0, VloT0, h,
      wo, bo, ln1g, ln1b,
      W1B1, W1B2, W2h, W2l, ffb1, ffb2, ln2g, ln2b,
      wqkv + 42 * 14, bqkv + 42,
      Qpack1, KB1_1, KB2_1, VhiT1, VloT1);

  layer1_tail<<<512, 512, 0, stream>>>(
      Qpack1, KB1_1, KB2_1, VhiT1, VloT1, h,
      wo + 196, bo + 14, ln1g + 14, ln1b + 14,
      W1B1 + (size_t)2048 * 16, W1B2 + (size_t)2048 * 16,
      W2h + (size_t)16 * FF, W2l + (size_t)16 * FF,
      ffb1 + FF, ffb2 + 14, ln2g + 14, ln2b + 14,
      fc1w, fc1b, fc2w, fc2b, x, y,
      B3h, B3l, fc3b, B4h, B4l, fc4b,
      fc5w, fc5b, out, out + NN);
}

// Round 6
// 234.558 us; speedup vs baseline: 1.2194x; 1.2194x over previous
//
#include <hip/hip_runtime.h>
#include <math.h>

#define NN 8192
#define DD 14
#define DP 16
#define FF 2048
#define HID 256
#define LN_EPS 1e-5f
#define QSCALE (1.4426950408889634f / 3.7416573867739413f)  // log2(e)/sqrt(14)

typedef short bf16x8 __attribute__((ext_vector_type(8)));
typedef float f32x4 __attribute__((ext_vector_type(4)));

#define LOAD16(dst, srcp) { \
  const float4* _p = (const float4*)(srcp); \
  float4 _a = _p[0], _b = _p[1], _c = _p[2], _d = _p[3]; \
  dst[0]=_a.x; dst[1]=_a.y; dst[2]=_a.z; dst[3]=_a.w; \
  dst[4]=_b.x; dst[5]=_b.y; dst[6]=_b.z; dst[7]=_b.w; \
  dst[8]=_c.x; dst[9]=_c.y; dst[10]=_c.z; dst[11]=_c.w; \
  dst[12]=_d.x; dst[13]=_d.y; dst[14]=_d.z; dst[15]=_d.w; }

#define STORE16(dstp, src) { \
  float4* _p = (float4*)(dstp); \
  _p[0] = make_float4(src[0], src[1], src[2], src[3]); \
  _p[1] = make_float4(src[4], src[5], src[6], src[7]); \
  _p[2] = make_float4(src[8], src[9], src[10], src[11]); \
  _p[3] = make_float4(src[12], src[13], src[14], src[15]); }

static __device__ __forceinline__ float fast_exp2(float x) {
#if __has_builtin(__builtin_amdgcn_exp2f)
  return __builtin_amdgcn_exp2f(x);
#else
  return exp2f(x);
#endif
}

static __device__ __forceinline__ unsigned short bf_hi(float x) {
  return (unsigned short)(__float_as_uint(x) >> 16);
}
static __device__ __forceinline__ float bf_hi_f(float x) {
  return __uint_as_float(__float_as_uint(x) & 0xffff0000u);
}

// ---- repack 8 floats -> bf16 hi/lo fragments ----
static __device__ __forceinline__ void split8(const float* pv, bf16x8* ph, bf16x8* pl) {
  #pragma unroll
  for (int i = 0; i < 8; i++) {
    unsigned int u = __float_as_uint(pv[i]);
    (*ph)[i] = (short)(u >> 16);
    float rr = pv[i] - __uint_as_float(u & 0xffff0000u);
    (*pl)[i] = (short)(__float_as_uint(rr) >> 16);
  }
}

// ---- shared helper: compute qkv for row r from hr[16], store packed operands ----
static __device__ __forceinline__ void qkv_compute_store(
    int r, const float* hr, const float* __restrict__ wqkv,
    const float* __restrict__ bqkv, unsigned int* __restrict__ Qpack,
    unsigned int* __restrict__ KB1, unsigned int* __restrict__ KB2,
    unsigned short* __restrict__ VhiT, unsigned short* __restrict__ VloT) {
  float q[14], k[14], v[14];
  #pragma unroll 6
  for (int c = 0; c < 42; c++) {
    const float* w = wqkv + c * 14;
    float s = bqkv[c];
    #pragma unroll
    for (int d = 0; d < 14; d++) s = fmaf(hr[d], w[d], s);
    if (c < 14)       q[c] = s * QSCALE;
    else if (c < 28)  k[c - 14] = s;
    else              v[c - 28] = s;
  }
  unsigned int qp[16], k1[16], k2[16];
  unsigned short qh[14], ql[14], kh[14], kl[14];
  #pragma unroll
  for (int d = 0; d < 14; d++) {
    qh[d] = bf_hi(q[d]);
    ql[d] = bf_hi(q[d] - bf_hi_f(q[d]));
    kh[d] = bf_hi(k[d]);
    kl[d] = bf_hi(k[d] - bf_hi_f(k[d]));
  }
  #pragma unroll
  for (int i = 0; i < 7; i++) {
    qp[i]     = (unsigned int)qh[2*i] | ((unsigned int)qh[2*i+1] << 16);
    qp[8 + i] = (unsigned int)ql[2*i] | ((unsigned int)ql[2*i+1] << 16);
    k1[i]     = (unsigned int)kh[2*i] | ((unsigned int)kh[2*i+1] << 16);
    k1[8 + i] = k1[i];
    k2[i]     = (unsigned int)kl[2*i] | ((unsigned int)kl[2*i+1] << 16);
    k2[8 + i] = k2[i];
  }
  qp[7] = 0; qp[15] = 0; k1[7] = 0; k1[15] = 0; k2[7] = 0; k2[15] = 0;
  uint4* Qp4 = (uint4*)(Qpack + (size_t)r * 16);
  uint4* K14 = (uint4*)(KB1 + (size_t)r * 16);
  uint4* K24 = (uint4*)(KB2 + (size_t)r * 16);
  #pragma unroll
  for (int i = 0; i < 4; i++) {
    Qp4[i] = make_uint4(qp[4*i], qp[4*i+1], qp[4*i+2], qp[4*i+3]);
    K14[i] = make_uint4(k1[4*i], k1[4*i+1], k1[4*i+2], k1[4*i+3]);
    K24[i] = make_uint4(k2[4*i], k2[4*i+1], k2[4*i+2], k2[4*i+3]);
  }
  #pragma unroll
  for (int d = 0; d < 14; d++) {
    VhiT[(size_t)d * NN + r] = bf_hi(v[d]);
    VloT[(size_t)d * NN + r] = bf_hi(v[d] - bf_hi_f(v[d]));
  }
  VhiT[(size_t)14 * NN + r] = 0x3F80;  // ones column = softmax denom
  VhiT[(size_t)15 * NN + r] = 0;
  VloT[(size_t)14 * NN + r] = 0;
  VloT[(size_t)15 * NN + r] = 0;
}

// ---- shared helper: A-operand pack of 14-dim vector (hi|lo) ----
static __device__ __forceinline__ void store_apack(unsigned int* dst, const float* o) {
  unsigned int qp[16];
  unsigned short hh[14], ll[14];
  #pragma unroll
  for (int d = 0; d < 14; d++) {
    hh[d] = bf_hi(o[d]);
    ll[d] = bf_hi(o[d] - bf_hi_f(o[d]));
  }
  #pragma unroll
  for (int i = 0; i < 7; i++) {
    qp[i]     = (unsigned int)hh[2*i] | ((unsigned int)hh[2*i+1] << 16);
    qp[8 + i] = (unsigned int)ll[2*i] | ((unsigned int)ll[2*i+1] << 16);
  }
  qp[7] = 0; qp[15] = 0;
  uint4* d4 = (uint4*)dst;
  #pragma unroll
  for (int i = 0; i < 4; i++)
    d4[i] = make_uint4(qp[4*i], qp[4*i+1], qp[4*i+2], qp[4*i+3]);
}

// ---- combine + LN (out-proj variant) ----
static __device__ __forceinline__ void combine_ln1(
    const float* srow, const float* hr, const float* __restrict__ wo,
    const float* __restrict__ bo, const float* __restrict__ g,
    const float* __restrict__ b, float* o) {
  float L = srow[14];
  float inv = 1.f / L;
  float a[14];
  #pragma unroll
  for (int d = 0; d < 14; d++) a[d] = srow[d] * inv;
  float xx[14];
  #pragma unroll
  for (int i = 0; i < 14; i++) {
    float s = bo[i];
    #pragma unroll
    for (int d = 0; d < 14; d++) s = fmaf(wo[i * 14 + d], a[d], s);
    xx[i] = hr[i] + s;
  }
  float mu = 0.f;
  #pragma unroll
  for (int i = 0; i < 14; i++) mu += xx[i];
  mu *= (1.f / 14.f);
  float var = 0.f;
  #pragma unroll
  for (int i = 0; i < 14; i++) { float tt = xx[i] - mu; var = fmaf(tt, tt, var); }
  var *= (1.f / 14.f);
  float rs = rsqrtf(var + LN_EPS);
  #pragma unroll
  for (int i = 0; i < 14; i++) o[i] = fmaf((xx[i] - mu) * rs, g[i], b[i]);
  o[14] = 0.f; o[15] = 0.f;
}

// ======================================================================
// K1: weight packs (fc3/fc4/ffn) + layer-0 qkv from x  (unchanged, proven)
// ======================================================================
__global__ void pack_all(const float* __restrict__ w3, const float* __restrict__ w4,
                         const float* __restrict__ ffw1, const float* __restrict__ ffw2,
                         const float* __restrict__ x, const float* __restrict__ wqkv,
                         const float* __restrict__ bqkv, float* __restrict__ h,
                         unsigned int* __restrict__ Qpack,
                         unsigned int* __restrict__ KB1, unsigned int* __restrict__ KB2,
                         unsigned short* __restrict__ VhiT, unsigned short* __restrict__ VloT,
                         unsigned short* __restrict__ B3h, unsigned short* __restrict__ B3l,
                         unsigned short* __restrict__ B4h, unsigned short* __restrict__ B4l,
                         unsigned int* __restrict__ W1B1, unsigned int* __restrict__ W1B2,
                         unsigned short* __restrict__ W2h, unsigned short* __restrict__ W2l) {
  const int blk = blockIdx.x, tid = threadIdx.x;
  if (blk < 32) {
    int t = blk * 256 + tid;
    int lane = t & 63, ks = (t >> 6) & 7, nt = t >> 9;
    int n = nt * 16 + (lane & 15);
    int k0 = ks * 32 + (lane >> 4) * 8;
    unsigned int h4[4], l4[4];
    #pragma unroll
    for (int jj = 0; jj < 4; jj++) {
      unsigned short h2[2], l2[2];
      #pragma unroll
      for (int e = 0; e < 2; e++) {
        float v = w4[(size_t)n * 256 + k0 + jj * 2 + e];
        h2[e] = bf_hi(v);
        l2[e] = bf_hi(v - bf_hi_f(v));
      }
      h4[jj] = (unsigned int)h2[0] | ((unsigned int)h2[1] << 16);
      l4[jj] = (unsigned int)l2[0] | ((unsigned int)l2[1] << 16);
    }
    ((uint4*)B4h)[t] = make_uint4(h4[0], h4[1], h4[2], h4[3]);
    ((uint4*)B4l)[t] = make_uint4(l4[0], l4[1], l4[2], l4[3]);
    if (ks < 2) {
      int fi = (nt * 2 + ks) * 64 + lane;
      #pragma unroll
      for (int jj = 0; jj < 4; jj++) {
        unsigned short h2[2], l2[2];
        #pragma unroll
        for (int e = 0; e < 2; e++) {
          int k = k0 + jj * 2 + e;
          float v = (k < 51) ? w3[(size_t)n * 51 + k] : 0.f;
          h2[e] = bf_hi(v);
          l2[e] = bf_hi(v - bf_hi_f(v));
        }
        h4[jj] = (unsigned int)h2[0] | ((unsigned int)h2[1] << 16);
        l4[jj] = (unsigned int)l2[0] | ((unsigned int)l2[1] << 16);
      }
      ((uint4*)B3h)[fi] = make_uint4(h4[0], h4[1], h4[2], h4[3]);
      ((uint4*)B3l)[fi] = make_uint4(l4[0], l4[1], l4[2], l4[3]);
    }
  } else if (blk < 48) {
    int t = (blk - 32) * 256 + tid;
    int l = t >> 11, j = t & 2047;
    const float* wrow = ffw1 + ((size_t)l * FF + j) * 14;
    unsigned int k1[16], k2[16];
    unsigned short kh[14], kl[14];
    #pragma unroll
    for (int d = 0; d < 14; d++) {
      float v = wrow[d];
      kh[d] = bf_hi(v);
      kl[d] = bf_hi(v - bf_hi_f(v));
    }
    #pragma unroll
    for (int i = 0; i < 7; i++) {
      k1[i] = (unsigned int)kh[2*i] | ((unsigned int)kh[2*i+1] << 16);
      k1[8 + i] = k1[i];
      k2[i] = (unsigned int)kl[2*i] | ((unsigned int)kl[2*i+1] << 16);
      k2[8 + i] = k2[i];
    }
    k1[7] = 0; k1[15] = 0; k2[7] = 0; k2[15] = 0;
    uint4* d1 = (uint4*)(W1B1 + (size_t)t * 16);
    uint4* d2 = (uint4*)(W1B2 + (size_t)t * 16);
    #pragma unroll
    for (int i = 0; i < 4; i++) {
      d1[i] = make_uint4(k1[4*i], k1[4*i+1], k1[4*i+2], k1[4*i+3]);
      d2[i] = make_uint4(k2[4*i], k2[4*i+1], k2[4*i+2], k2[4*i+3]);
    }
  } else if (blk < 64) {
    int t = (blk - 48) * 256 + tid;
    int l = t >> 11, j = t & 2047;
    #pragma unroll
    for (int d = 0; d < 16; d++) {
      float v = (d < 14) ? ffw2[((size_t)l * 14 + d) * FF + j] : 0.f;
      W2h[((size_t)l * 16 + d) * FF + j] = bf_hi(v);
      W2l[((size_t)l * 16 + d) * FF + j] = bf_hi(v - bf_hi_f(v));
    }
  } else {
    int r = (blk - 64) * 256 + tid;
    float hr[16];
    #pragma unroll
    for (int d = 0; d < 14; d++) hr[d] = x[(size_t)r * 14 + d];
    hr[14] = 0.f; hr[15] = 0.f;
    STORE16(h + (size_t)r * DP, hr);
    qkv_compute_store(r, hr, wqkv, bqkv, Qpack, KB1, KB2, VhiT, VloT);
  }
}

// ======================================================================
// Pipelined 32-row attention core with K/V REGISTER PREFETCH:
//  - chunk c+1's K/V fragments are loaded while chunk c computes
//  - V(c-1) kept in regs (pvh/pvl) for the PV step (no reload)
//  - LDS reads of P(c-1) issued before writes of P(c) (per-wave DS order)
// ======================================================================
static __device__ __forceinline__ void attn_core(
    const bf16x8* __restrict__ Qp, const bf16x8* __restrict__ B1,
    const bf16x8* __restrict__ B2, const bf16x8* __restrict__ Vh,
    const bf16x8* __restrict__ Vl, int qbase, int wave, int lo4, int hi4,
    float (*Pl)[36], f32x4* o0, f32x4* o1) {
  const f32x4 zero = {0.f, 0.f, 0.f, 0.f};
  bf16x8 aQ0 = Qp[(size_t)(qbase + lo4) * 4 + hi4];
  bf16x8 aQ1 = Qp[(size_t)(qbase + 16 + lo4) * 4 + hi4];
  f32x4 acc0 = zero, acc1 = zero;
  const int kstart = wave * 1024;
  const float4* p0 = (const float4*)&Pl[lo4][hi4 * 8];
  const float4* p1 = (const float4*)&Pl[16 + lo4][hi4 * 8];

  // prologue: chunk-0 fragments
  bf16x8 cb10 = B1[(size_t)(kstart + lo4) * 4 + hi4];
  bf16x8 cb20 = B2[(size_t)(kstart + lo4) * 4 + hi4];
  bf16x8 cb11 = B1[(size_t)(kstart + 16 + lo4) * 4 + hi4];
  bf16x8 cb21 = B2[(size_t)(kstart + 16 + lo4) * 4 + hi4];
  bf16x8 cvh = Vh[(size_t)lo4 * 1024 + (kstart >> 3) + hi4];
  bf16x8 cvl = Vl[(size_t)lo4 * 1024 + (kstart >> 3) + hi4];
  bf16x8 pvh = cvh, pvl = cvl;
  float4 ra0, ra1, rc0, rc1;

  for (int c = 0; c < 32; c++) {
    if (c > 0) {            // issue reads of P(c-1) early
      ra0 = p0[0]; ra1 = p0[1]; rc0 = p1[0]; rc1 = p1[1];
      __asm__ volatile("" ::: "memory");   // keep reads above the writes below
    }
    // prefetch chunk c+1 (clamped on last iter; loads stay in-bounds)
    const int kn = kstart + ((c < 31) ? (c + 1) * 32 : c * 32);
    bf16x8 nb10 = B1[(size_t)(kn + lo4) * 4 + hi4];
    bf16x8 nb20 = B2[(size_t)(kn + lo4) * 4 + hi4];
    bf16x8 nb11 = B1[(size_t)(kn + 16 + lo4) * 4 + hi4];
    bf16x8 nb21 = B2[(size_t)(kn + 16 + lo4) * 4 + hi4];
    bf16x8 nvh = Vh[(size_t)lo4 * 1024 + (kn >> 3) + hi4];
    bf16x8 nvl = Vl[(size_t)lo4 * 1024 + (kn >> 3) + hi4];

    f32x4 s00 = __builtin_amdgcn_mfma_f32_16x16x32_bf16(aQ0, cb10, zero, 0, 0, 0);
    f32x4 s01 = __builtin_amdgcn_mfma_f32_16x16x32_bf16(aQ0, cb11, zero, 0, 0, 0);
    f32x4 s10 = __builtin_amdgcn_mfma_f32_16x16x32_bf16(aQ1, cb10, zero, 0, 0, 0);
    f32x4 s11 = __builtin_amdgcn_mfma_f32_16x16x32_bf16(aQ1, cb11, zero, 0, 0, 0);
    s00 = __builtin_amdgcn_mfma_f32_16x16x32_bf16(aQ0, cb20, s00, 0, 0, 0);
    s01 = __builtin_amdgcn_mfma_f32_16x16x32_bf16(aQ0, cb21, s01, 0, 0, 0);
    s10 = __builtin_amdgcn_mfma_f32_16x16x32_bf16(aQ1, cb20, s10, 0, 0, 0);
    s11 = __builtin_amdgcn_mfma_f32_16x16x32_bf16(aQ1, cb21, s11, 0, 0, 0);
    // write P(c) (queued after the early reads -> reads return old data)
    #pragma unroll
    for (int reg = 0; reg < 4; reg++) {
      Pl[hi4 * 4 + reg][lo4]           = fast_exp2(s00[reg]);
      Pl[hi4 * 4 + reg][16 + lo4]      = fast_exp2(s01[reg]);
      Pl[16 + hi4 * 4 + reg][lo4]      = fast_exp2(s10[reg]);
      Pl[16 + hi4 * 4 + reg][16 + lo4] = fast_exp2(s11[reg]);
    }
    if (c > 0) {            // PV of chunk c-1 with registered V(c-1)
      float pv0[8] = {ra0.x, ra0.y, ra0.z, ra0.w, ra1.x, ra1.y, ra1.z, ra1.w};
      float pv1[8] = {rc0.x, rc0.y, rc0.z, rc0.w, rc1.x, rc1.y, rc1.z, rc1.w};
      bf16x8 ph0, pl0, ph1, pl1;
      split8(pv0, &ph0, &pl0);
      split8(pv1, &ph1, &pl1);
      acc0 = __builtin_amdgcn_mfma_f32_16x16x32_bf16(ph0, pvh, acc0, 0, 0, 0);
      acc1 = __builtin_amdgcn_mfma_f32_16x16x32_bf16(ph1, pvh, acc1, 0, 0, 0);
      acc0 = __builtin_amdgcn_mfma_f32_16x16x32_bf16(pl0, pvh, acc0, 0, 0, 0);
      acc1 = __builtin_amdgcn_mfma_f32_16x16x32_bf16(pl1, pvh, acc1, 0, 0, 0);
      acc0 = __builtin_amdgcn_mfma_f32_16x16x32_bf16(ph0, pvl, acc0, 0, 0, 0);
      acc1 = __builtin_amdgcn_mfma_f32_16x16x32_bf16(ph1, pvl, acc1, 0, 0, 0);
    }
    pvh = cvh; pvl = cvl;
    cb10 = nb10; cb20 = nb20; cb11 = nb11; cb21 = nb21;
    cvh = nvh; cvl = nvl;
  }
  // epilogue: PV of chunk 31 (pvh/pvl now hold V(31))
  {
    float4 a0 = p0[0], a1 = p0[1], c0 = p1[0], c1 = p1[1];
    float pv0[8] = {a0.x, a0.y, a0.z, a0.w, a1.x, a1.y, a1.z, a1.w};
    float pv1[8] = {c0.x, c0.y, c0.z, c0.w, c1.x, c1.y, c1.z, c1.w};
    bf16x8 ph0, pl0, ph1, pl1;
    split8(pv0, &ph0, &pl0);
    split8(pv1, &ph1, &pl1);
    acc0 = __builtin_amdgcn_mfma_f32_16x16x32_bf16(ph0, pvh, acc0, 0, 0, 0);
    acc1 = __builtin_amdgcn_mfma_f32_16x16x32_bf16(ph1, pvh, acc1, 0, 0, 0);
    acc0 = __builtin_amdgcn_mfma_f32_16x16x32_bf16(pl0, pvh, acc0, 0, 0, 0);
    acc1 = __builtin_amdgcn_mfma_f32_16x16x32_bf16(pl1, pvh, acc1, 0, 0, 0);
    acc0 = __builtin_amdgcn_mfma_f32_16x16x32_bf16(ph0, pvl, acc0, 0, 0, 0);
    acc1 = __builtin_amdgcn_mfma_f32_16x16x32_bf16(ph1, pvl, acc1, 0, 0, 0);
  }
  *o0 = acc0; *o1 = acc1;
}

// ======================================================================
// Pipelined 32-row FFN core with register prefetch (8 chunks of 32).
// ======================================================================
static __device__ __forceinline__ void ffn_core(
    bf16x8 aH0, bf16x8 aH1, const bf16x8* __restrict__ B1,
    const bf16x8* __restrict__ B2, const bf16x8* __restrict__ Vh,
    const bf16x8* __restrict__ Vl, const float* __restrict__ b1,
    int jstart, int lo4, int hi4, float (*Pl)[36], f32x4* o0, f32x4* o1) {
  const f32x4 zero = {0.f, 0.f, 0.f, 0.f};
  f32x4 acc0 = zero, acc1 = zero;
  const float4* p0 = (const float4*)&Pl[lo4][hi4 * 8];
  const float4* p1 = (const float4*)&Pl[16 + lo4][hi4 * 8];

  bf16x8 cb10 = B1[(size_t)(jstart + lo4) * 4 + hi4];
  bf16x8 cb20 = B2[(size_t)(jstart + lo4) * 4 + hi4];
  bf16x8 cb11 = B1[(size_t)(jstart + 16 + lo4) * 4 + hi4];
  bf16x8 cb21 = B2[(size_t)(jstart + 16 + lo4) * 4 + hi4];
  bf16x8 cvh = Vh[(size_t)lo4 * 256 + (jstart >> 3) + hi4];
  bf16x8 cvl = Vl[(size_t)lo4 * 256 + (jstart >> 3) + hi4];
  float cbb0 = b1[jstart + lo4];
  float cbb1 = b1[jstart + 16 + lo4];
  bf16x8 pvh = cvh, pvl = cvl;
  float4 ra0, ra1, rc0, rc1;

  for (int c = 0; c < 8; c++) {
    if (c > 0) {
      ra0 = p0[0]; ra1 = p0[1]; rc0 = p1[0]; rc1 = p1[1];
      __asm__ volatile("" ::: "memory");
    }
    const int jn = jstart + ((c < 7) ? (c + 1) * 32 : c * 32);
    bf16x8 nb10 = B1[(size_t)(jn + lo4) * 4 + hi4];
    bf16x8 nb20 = B2[(size_t)(jn + lo4) * 4 + hi4];
    bf16x8 nb11 = B1[(size_t)(jn + 16 + lo4) * 4 + hi4];
    bf16x8 nb21 = B2[(size_t)(jn + 16 + lo4) * 4 + hi4];
    bf16x8 nvh = Vh[(size_t)lo4 * 256 + (jn >> 3) + hi4];
    bf16x8 nvl = Vl[(size_t)lo4 * 256 + (jn >> 3) + hi4];
    float nbb0 = b1[jn + lo4];
    float nbb1 = b1[jn + 16 + lo4];

    f32x4 s00 = __builtin_amdgcn_mfma_f32_16x16x32_bf16(aH0, cb10, zero, 0, 0, 0);
    f32x4 s01 = __builtin_amdgcn_mfma_f32_16x16x32_bf16(aH0, cb11, zero, 0, 0, 0);
    f32x4 s10 = __builtin_amdgcn_mfma_f32_16x16x32_bf16(aH1, cb10, zero, 0, 0, 0);
    f32x4 s11 = __builtin_amdgcn_mfma_f32_16x16x32_bf16(aH1, cb11, zero, 0, 0, 0);
    s00 = __builtin_amdgcn_mfma_f32_16x16x32_bf16(aH0, cb20, s00, 0, 0, 0);
    s01 = __builtin_amdgcn_mfma_f32_16x16x32_bf16(aH0, cb21, s01, 0, 0, 0);
    s10 = __builtin_amdgcn_mfma_f32_16x16x32_bf16(aH1, cb20, s10, 0, 0, 0);
    s11 = __builtin_amdgcn_mfma_f32_16x16x32_bf16(aH1, cb21, s11, 0, 0, 0);
    #pragma unroll
    for (int reg = 0; reg < 4; reg++) {
      Pl[hi4 * 4 + reg][lo4]           = fmaxf(s00[reg] + cbb0, 0.f);
      Pl[hi4 * 4 + reg][16 + lo4]      = fmaxf(s01[reg] + cbb1, 0.f);
      Pl[16 + hi4 * 4 + reg][lo4]      = fmaxf(s10[reg] + cbb0, 0.f);
      Pl[16 + hi4 * 4 + reg][16 + lo4] = fmaxf(s11[reg] + cbb1, 0.f);
    }
    if (c > 0) {
      float pv0[8] = {ra0.x, ra0.y, ra0.z, ra0.w, ra1.x, ra1.y, ra1.z, ra1.w};
      float pv1[8] = {rc0.x, rc0.y, rc0.z, rc0.w, rc1.x, rc1.y, rc1.z, rc1.w};
      bf16x8 th0, tl0, th1, tl1;
      split8(pv0, &th0, &tl0);
      split8(pv1, &th1, &tl1);
      acc0 = __builtin_amdgcn_mfma_f32_16x16x32_bf16(th0, pvh, acc0, 0, 0, 0);
      acc1 = __builtin_amdgcn_mfma_f32_16x16x32_bf16(th1, pvh, acc1, 0, 0, 0);
      acc0 = __builtin_amdgcn_mfma_f32_16x16x32_bf16(tl0, pvh, acc0, 0, 0, 0);
      acc1 = __builtin_amdgcn_mfma_f32_16x16x32_bf16(tl1, pvh, acc1, 0, 0, 0);
      acc0 = __builtin_amdgcn_mfma_f32_16x16x32_bf16(th0, pvl, acc0, 0, 0, 0);
      acc1 = __builtin_amdgcn_mfma_f32_16x16x32_bf16(th1, pvl, acc1, 0, 0, 0);
    }
    pvh = cvh; pvl = cvl;
    cb10 = nb10; cb20 = nb20; cb11 = nb11; cb21 = nb21;
    cvh = nvh; cvl = nvl; cbb0 = nbb0; cbb1 = nbb1;
  }
  {
    float4 a0 = p0[0], a1 = p0[1], c0 = p1[0], c1 = p1[1];
    float pv0[8] = {a0.x, a0.y, a0.z, a0.w, a1.x, a1.y, a1.z, a1.w};
    float pv1[8] = {c0.x, c0.y, c0.z, c0.w, c1.x, c1.y, c1.z, c1.w};
    bf16x8 th0, tl0, th1, tl1;
    split8(pv0, &th0, &tl0);
    split8(pv1, &th1, &tl1);
    acc0 = __builtin_amdgcn_mfma_f32_16x16x32_bf16(th0, pvh, acc0, 0, 0, 0);
    acc1 = __builtin_amdgcn_mfma_f32_16x16x32_bf16(th1, pvh, acc1, 0, 0, 0);
    acc0 = __builtin_amdgcn_mfma_f32_16x16x32_bf16(tl0, pvh, acc0, 0, 0, 0);
    acc1 = __builtin_amdgcn_mfma_f32_16x16x32_bf16(tl1, pvh, acc1, 0, 0, 0);
    acc0 = __builtin_amdgcn_mfma_f32_16x16x32_bf16(th0, pvl, acc0, 0, 0, 0);
    acc1 = __builtin_amdgcn_mfma_f32_16x16x32_bf16(th1, pvl, acc1, 0, 0, 0);
  }
  *o0 = acc0; *o1 = acc1;
}

// LDS layout (bytes):
//   0      : Plds  8 x [32][36] f32   (36864)      } tail phase reuses 0..51200
//   36864  : sacc  [8][32][16] f32    (16384)
//   53248  : hrow  [32][16] f32       (2048)
//   55296  : Hl    [32][16] u32       (2048)
//   57344  : szf   [32] f32           (128)   -> total 57472
#define SMEM_BYTES 57472

// ======================================================================
// K2: layer 0 = attn + combine/LN1 (LDS) + ffn + LN2 + layer-1 qkv pack.
// ======================================================================
__global__ __launch_bounds__(512, 2) void layer0_fused(
    const unsigned int* __restrict__ Qpack, const unsigned int* __restrict__ KB1,
    const unsigned int* __restrict__ KB2, const unsigned short* __restrict__ VhiT,
    const unsigned short* __restrict__ VloT, float* __restrict__ h,
    const float* __restrict__ wo, const float* __restrict__ bo,
    const float* __restrict__ g1, const float* __restrict__ b1n,
    const unsigned int* __restrict__ W1B1, const unsigned int* __restrict__ W1B2,
    const unsigned short* __restrict__ W2h, const unsigned short* __restrict__ W2l,
    const float* __restrict__ fb1, const float* __restrict__ fb2,
    const float* __restrict__ g2, const float* __restrict__ b2n,
    const float* __restrict__ wqkv1, const float* __restrict__ bqkv1,
    unsigned int* __restrict__ Qpack1, unsigned int* __restrict__ KB1_1,
    unsigned int* __restrict__ KB2_1, unsigned short* __restrict__ VhiT1,
    unsigned short* __restrict__ VloT1) {
  __shared__ alignas(16) char smem[SMEM_BYTES];
  const int tid = threadIdx.x;
  const int wave = tid >> 6;
  const int lane = tid & 63;
  const int lo4 = lane & 15;
  const int hi4 = lane >> 4;
  const int qbase = blockIdx.x * 32;

  float (*Pl)[36] = (float(*)[36])(smem + wave * 4608);
  float (*sacc)[32][16] = (float(*)[32][16])(smem + 36864);
  float (*hrow)[16] = (float(*)[16])(smem + 53248);
  unsigned int (*Hl)[16] = (unsigned int(*)[16])(smem + 55296);

  // ---- phase A: attention ----
  f32x4 a0, a1;
  attn_core((const bf16x8*)Qpack, (const bf16x8*)KB1, (const bf16x8*)KB2,
            (const bf16x8*)VhiT, (const bf16x8*)VloT, qbase, wave, lo4, hi4,
            Pl, &a0, &a1);
  #pragma unroll
  for (int reg = 0; reg < 4; reg++) {
    sacc[wave][hi4 * 4 + reg][lo4] = a0[reg];
    sacc[wave][16 + hi4 * 4 + reg][lo4] = a1[reg];
  }
  __syncthreads();
  {
    int qq = tid >> 4, col = tid & 15;
    float v = 0.f;
    #pragma unroll
    for (int w = 0; w < 8; w++) v += sacc[w][qq][col];
    sacc[0][qq][col] = v;
  }
  __syncthreads();
  if (tid < 32) {
    int r = qbase + tid;
    float hr[16];
    LOAD16(hr, h + (size_t)r * DP);
    float o[16];
    combine_ln1(&sacc[0][tid][0], hr, wo, bo, g1, b1n, o);
    #pragma unroll
    for (int i = 0; i < 16; i++) hrow[tid][i] = o[i];
    store_apack(&Hl[tid][0], o);
  }
  __syncthreads();

  // ---- phase B: FFN ----
  bf16x8 aH0 = *(const bf16x8*)&Hl[lo4][hi4 * 4];
  bf16x8 aH1 = *(const bf16x8*)&Hl[16 + lo4][hi4 * 4];
  f32x4 f0, f1;
  ffn_core(aH0, aH1, (const bf16x8*)W1B1, (const bf16x8*)W1B2,
           (const bf16x8*)W2h, (const bf16x8*)W2l, fb1, wave * 256,
           lo4, hi4, Pl, &f0, &f1);
  __syncthreads();
  #pragma unroll
  for (int reg = 0; reg < 4; reg++) {
    sacc[wave][hi4 * 4 + reg][lo4] = f0[reg];
    sacc[wave][16 + hi4 * 4 + reg][lo4] = f1[reg];
  }
  __syncthreads();
  {
    int qq = tid >> 4, col = tid & 15;
    float v = 0.f;
    #pragma unroll
    for (int w = 0; w < 8; w++) v += sacc[w][qq][col];
    sacc[0][qq][col] = v;
  }
  __syncthreads();
  if (tid < 32) {
    int r = qbase + tid;
    float xx[14];
    #pragma unroll
    for (int i = 0; i < 14; i++) xx[i] = hrow[tid][i] + sacc[0][tid][i] + fb2[i];
    float mu = 0.f;
    #pragma unroll
    for (int i = 0; i < 14; i++) mu += xx[i];
    mu *= (1.f / 14.f);
    float var = 0.f;
    #pragma unroll
    for (int i = 0; i < 14; i++) { float tt = xx[i] - mu; var = fmaf(tt, tt, var); }
    var *= (1.f / 14.f);
    float rs = rsqrtf(var + LN_EPS);
    float o[16];
    #pragma unroll
    for (int i = 0; i < 14; i++) o[i] = fmaf((xx[i] - mu) * rs, g2[i], b2n[i]);
    o[14] = 0.f; o[15] = 0.f;
    STORE16(h + (size_t)r * DP, o);
    qkv_compute_store(r, o, wqkv1, bqkv1, Qpack1, KB1_1, KB2_1, VhiT1, VloT1);
  }
}

// ======================================================================
// K3: layer 1 = attn + LN1 + ffn + LN2 + size head + regression tail.
// 32 rows/block; tail runs as two 16-row groups (waves 0-3 / 4-7).
// ======================================================================
__global__ __launch_bounds__(512, 2) void layer1_tail(
    const unsigned int* __restrict__ Qpack, const unsigned int* __restrict__ KB1,
    const unsigned int* __restrict__ KB2, const unsigned short* __restrict__ VhiT,
    const unsigned short* __restrict__ VloT, const float* __restrict__ h,
    const float* __restrict__ wo, const float* __restrict__ bo,
    const float* __restrict__ g1, const float* __restrict__ b1n,
    const unsigned int* __restrict__ W1B1, const unsigned int* __restrict__ W1B2,
    const unsigned short* __restrict__ W2h, const unsigned short* __restrict__ W2l,
    const float* __restrict__ fb1, const float* __restrict__ fb2,
    const float* __restrict__ g2, const float* __restrict__ b2n,
    const float* __restrict__ fc1w, const float* __restrict__ fc1b,
    const float* __restrict__ fc2w, const float* __restrict__ fc2b,
    const float* __restrict__ x, const float* __restrict__ y,
    const unsigned short* __restrict__ B3h, const unsigned short* __restrict__ B3l,
    const float* __restrict__ b3,
    const unsigned short* __restrict__ B4h, const unsigned short* __restrict__ B4l,
    const float* __restrict__ b4,
    const float* __restrict__ w5, const float* __restrict__ b5,
    float* __restrict__ out, float* __restrict__ outr) {
  __shared__ alignas(16) char smem[SMEM_BYTES];
  const int tid = threadIdx.x;
  const int wave = tid >> 6;
  const int lane = tid & 63;
  const int lo4 = lane & 15;
  const int hi4 = lane >> 4;
  const int qbase = blockIdx.x * 32;
  const f32x4 zero = {0.f, 0.f, 0.f, 0.f};

  float (*Pl)[36] = (float(*)[36])(smem + wave * 4608);
  float (*sacc)[32][16] = (float(*)[32][16])(smem + 36864);
  float (*hrow)[16] = (float(*)[16])(smem + 53248);
  unsigned int (*Hl)[16] = (unsigned int(*)[16])(smem + 55296);
  float* szf = (float*)(smem + 57344);

  // ---- phase A: attention (layer 1) ----
  f32x4 a0, a1;
  attn_core((const bf16x8*)Qpack, (const bf16x8*)KB1, (const bf16x8*)KB2,
            (const bf16x8*)VhiT, (const bf16x8*)VloT, qbase, wave, lo4, hi4,
            Pl, &a0, &a1);
  #pragma unroll
  for (int reg = 0; reg < 4; reg++) {
    sacc[wave][hi4 * 4 + reg][lo4] = a0[reg];
    sacc[wave][16 + hi4 * 4 + reg][lo4] = a1[reg];
  }
  __syncthreads();
  {
    int qq = tid >> 4, col = tid & 15;
    float v = 0.f;
    #pragma unroll
    for (int w = 0; w < 8; w++) v += sacc[w][qq][col];
    sacc[0][qq][col] = v;
  }
  __syncthreads();
  if (tid < 32) {
    int r = qbase + tid;
    float hr[16];
    LOAD16(hr, h + (size_t)r * DP);
    float o[16];
    combine_ln1(&sacc[0][tid][0], hr, wo, bo, g1, b1n, o);
    #pragma unroll
    for (int i = 0; i < 16; i++) hrow[tid][i] = o[i];
    store_apack(&Hl[tid][0], o);
  }
  __syncthreads();

  // ---- phase B: FFN (layer 1) + LN2 + size head ----
  bf16x8 aH0 = *(const bf16x8*)&Hl[lo4][hi4 * 4];
  bf16x8 aH1 = *(const bf16x8*)&Hl[16 + lo4][hi4 * 4];
  f32x4 f0, f1;
  ffn_core(aH0, aH1, (const bf16x8*)W1B1, (const bf16x8*)W1B2,
           (const bf16x8*)W2h, (const bf16x8*)W2l, fb1, wave * 256,
           lo4, hi4, Pl, &f0, &f1);
  __syncthreads();
  #pragma unroll
  for (int reg = 0; reg < 4; reg++) {
    sacc[wave][hi4 * 4 + reg][lo4] = f0[reg];
    sacc[wave][16 + hi4 * 4 + reg][lo4] = f1[reg];
  }
  __syncthreads();
  {
    int qq = tid >> 4, col = tid & 15;
    float v = 0.f;
    #pragma unroll
    for (int w = 0; w < 8; w++) v += sacc[w][qq][col];
    sacc[0][qq][col] = v;
  }
  __syncthreads();
  if (tid < 32) {
    int r = qbase + tid;
    float xx[14];
    #pragma unroll
    for (int i = 0; i < 14; i++) xx[i] = hrow[tid][i] + sacc[0][tid][i] + fb2[i];
    float mu = 0.f;
    #pragma unroll
    for (int i = 0; i < 14; i++) mu += xx[i];
    mu *= (1.f / 14.f);
    float var = 0.f;
    #pragma unroll
    for (int i = 0; i < 14; i++) { float tt = xx[i] - mu; var = fmaf(tt, tt, var); }
    var *= (1.f / 14.f);
    float rs = rsqrtf(var + LN_EPS);
    float o[14];
    #pragma unroll
    for (int i = 0; i < 14; i++) o[i] = fmaf((xx[i] - mu) * rs, g2[i], b2n[i]);
    float s = fc2b[0];
    #pragma unroll
    for (int i = 0; i < 14; i++) {
      float tt = fc1b[i];
      #pragma unroll
      for (int d = 0; d < 14; d++) tt = fmaf(fc1w[i * 14 + d], o[d], tt);
      s = fmaf(tt, fc2w[i], s);
    }
    out[r] = s;
    int si = (int)s;  // trunc toward zero, matches astype(int32)
    szf[tid] = (float)si;
  }
  __syncthreads();

  // ---- phase C: regression head, two 16-row groups ----
  const int grp = wave >> 2;   // 0 or 1: rows [qbase+grp*16, +16)
  const int wg  = wave & 3;    // wave-in-group

  for (int idx = tid; idx < 2 * 16 * 64; idx += 512) {
    int g = idx >> 10, m = (idx >> 6) & 15, k = idx & 63;
    int r = qbase + g * 16 + m;
    float v = 0.f;
    if (k == 0)       v = szf[g * 16 + m];
    else if (k < 15)  v = x[(size_t)r * 14 + (k - 1)];
    else if (k < 51)  v = y[(size_t)r * 36 + (k - 15)];
    ((unsigned short(*)[72])(smem + g * 2304))[m][k] = bf_hi(v);
    ((unsigned short(*)[72])(smem + 4608 + g * 2304))[m][k] = bf_hi(v - bf_hi_f(v));
  }
  __syncthreads();

  unsigned short (*Ah)[72]  = (unsigned short(*)[72])(smem + grp * 2304);
  unsigned short (*Al)[72]  = (unsigned short(*)[72])(smem + 4608 + grp * 2304);
  unsigned short (*R1h)[264] = (unsigned short(*)[264])(smem + 9216 + grp * 8448);
  unsigned short (*R1l)[264] = (unsigned short(*)[264])(smem + 26112 + grp * 8448);
  float (*sred)[16][16] = (float(*)[16][16])(smem + 43008 + (size_t)grp * 4096);

  f32x4 acc[4];
  #pragma unroll
  for (int nt = 0; nt < 4; nt++) acc[nt] = zero;
  #pragma unroll
  for (int ks = 0; ks < 2; ks++) {
    bf16x8 ah = *(const bf16x8*)&Ah[lo4][ks * 32 + hi4 * 8];
    bf16x8 al = *(const bf16x8*)&Al[lo4][ks * 32 + hi4 * 8];
    #pragma unroll
    for (int nt = 0; nt < 4; nt++) {
      int fi = ((wg * 4 + nt) * 2 + ks) * 64 + lane;
      bf16x8 bh = ((const bf16x8*)B3h)[fi];
      bf16x8 bl = ((const bf16x8*)B3l)[fi];
      acc[nt] = __builtin_amdgcn_mfma_f32_16x16x32_bf16(ah, bh, acc[nt], 0, 0, 0);
      acc[nt] = __builtin_amdgcn_mfma_f32_16x16x32_bf16(al, bh, acc[nt], 0, 0, 0);
      acc[nt] = __builtin_amdgcn_mfma_f32_16x16x32_bf16(ah, bl, acc[nt], 0, 0, 0);
    }
  }
  #pragma unroll
  for (int nt = 0; nt < 4; nt++) {
    int n = (wg * 4 + nt) * 16 + lo4;
    float bbv = b3[n];
    #pragma unroll
    for (int reg = 0; reg < 4; reg++) {
      int m = hi4 * 4 + reg;
      float v = fmaxf(acc[nt][reg] + bbv, 0.f);
      R1h[m][n] = bf_hi(v);
      R1l[m][n] = bf_hi(v - bf_hi_f(v));
    }
  }
  __syncthreads();

  #pragma unroll
  for (int nt = 0; nt < 4; nt++) acc[nt] = zero;
  #pragma unroll
  for (int ks = 0; ks < 8; ks++) {
    bf16x8 ah = *(const bf16x8*)&R1h[lo4][ks * 32 + hi4 * 8];
    bf16x8 al = *(const bf16x8*)&R1l[lo4][ks * 32 + hi4 * 8];
    #pragma unroll
    for (int nt = 0; nt < 4; nt++) {
      int fi = ((wg * 4 + nt) * 8 + ks) * 64 + lane;
      bf16x8 bh = ((const bf16x8*)B4h)[fi];
      bf16x8 bl = ((const bf16x8*)B4l)[fi];
      acc[nt] = __builtin_amdgcn_mfma_f32_16x16x32_bf16(ah, bh, acc[nt], 0, 0, 0);
      acc[nt] = __builtin_amdgcn_mfma_f32_16x16x32_bf16(al, bh, acc[nt], 0, 0, 0);
      acc[nt] = __builtin_amdgcn_mfma_f32_16x16x32_bf16(ah, bl, acc[nt], 0, 0, 0);
    }
  }
  float s4[4] = {0.f, 0.f, 0.f, 0.f};
  #pragma unroll
  for (int nt = 0; nt < 4; nt++) {
    int n = (wg * 4 + nt) * 16 + lo4;
    float bbv = b4[n], ww = w5[n];
    #pragma unroll
    for (int reg = 0; reg < 4; reg++)
      s4[reg] = fmaf(fmaxf(acc[nt][reg] + bbv, 0.f), ww, s4[reg]);
  }
  #pragma unroll
  for (int reg = 0; reg < 4; reg++) sred[wg][hi4 * 4 + reg][lo4] = s4[reg];
  __syncthreads();

  if (tid < 32) {
    int g = tid >> 4, m = tid & 15;
    float (*sredG)[16][16] = (float(*)[16][16])(smem + 43008 + (size_t)g * 4096);
    float t = b5[0];
    #pragma unroll
    for (int w = 0; w < 4; w++) {
      const float4* p = (const float4*)&sredG[w][m][0];
      float4 q0 = p[0], q1 = p[1], q2 = p[2], q3 = p[3];
      t += ((q0.x + q0.y) + (q0.z + q0.w)) + ((q1.x + q1.y) + (q1.z + q1.w)) +
           ((q2.x + q2.y) + (q2.z + q2.w)) + ((q3.x + q3.y) + (q3.z + q3.w));
    }
    float sz = szf[tid];
    outr[qbase + tid] = (sz != 0.f) ? t : 0.f;
  }
}

extern "C" void kernel_launch(void* const* d_in, const int* in_sizes, int n_in,
                              void* d_out, int out_size, void* d_ws, size_t ws_size,
                              hipStream_t stream) {
  const float* x    = (const float*)d_in[0];
  const float* y    = (const float*)d_in[1];
  const float* wqkv = (const float*)d_in[2];
  const float* bqkv = (const float*)d_in[3];
  const float* wo   = (const float*)d_in[4];
  const float* bo   = (const float*)d_in[5];
  const float* ln1g = (const float*)d_in[6];
  const float* ln1b = (const float*)d_in[7];
  const float* ffw1 = (const float*)d_in[8];
  const float* ffb1 = (const float*)d_in[9];
  const float* ffw2 = (const float*)d_in[10];
  const float* ffb2 = (const float*)d_in[11];
  const float* ln2g = (const float*)d_in[12];
  const float* ln2b = (const float*)d_in[13];
  const float* fc1w = (const float*)d_in[14];
  const float* fc1b = (const float*)d_in[15];
  const float* fc2w = (const float*)d_in[16];
  const float* fc2b = (const float*)d_in[17];
  const float* fc3w = (const float*)d_in[18];
  const float* fc3b = (const float*)d_in[19];
  const float* fc4w = (const float*)d_in[20];
  const float* fc4b = (const float*)d_in[21];
  const float* fc5w = (const float*)d_in[22];
  const float* fc5b = (const float*)d_in[23];

  float* ws = (float*)d_ws;
  float*          h      = ws;                               // 131072 f
  unsigned int*   Qpack0 = (unsigned int*)(ws + 131072);
  unsigned int*   KB1_0  = (unsigned int*)(ws + 262144);
  unsigned int*   KB2_0  = (unsigned int*)(ws + 393216);
  unsigned short* VhiT0  = (unsigned short*)(ws + 524288);
  unsigned short* VloT0  = (unsigned short*)(ws + 589824);
  unsigned int*   Qpack1 = (unsigned int*)(ws + 786432);
  unsigned int*   KB1_1  = (unsigned int*)(ws + 917504);
  unsigned int*   KB2_1  = (unsigned int*)(ws + 1048576);
  unsigned short* VhiT1  = (unsigned short*)(ws + 1179648);
  unsigned short* VloT1  = (unsigned short*)(ws + 1245184);
  unsigned short* B3h    = (unsigned short*)(ws + 2891776);
  unsigned short* B3l    = (unsigned short*)(ws + 2899968);
  unsigned short* B4h    = (unsigned short*)(ws + 2908160);
  unsigned short* B4l    = (unsigned short*)(ws + 2940928);
  unsigned int*   W1B1   = (unsigned int*)(ws + 2973696);
  unsigned int*   W1B2   = (unsigned int*)(ws + 3039232);
  unsigned short* W2h    = (unsigned short*)(ws + 3104768);
  unsigned short* W2l    = (unsigned short*)(ws + 3137536);

  float* out = (float*)d_out;

  pack_all<<<96, 256, 0, stream>>>(fc3w, fc4w, ffw1, ffw2, x, wqkv, bqkv, h,
                                   Qpack0, KB1_0, KB2_0, VhiT0, VloT0,
                                   B3h, B3l, B4h, B4l, W1B1, W1B2, W2h, W2l);

  layer0_fused<<<256, 512, 0, stream>>>(
      Qpack0, KB1_0, KB2_0, VhiT0, VloT0, h,
      wo, bo, ln1g, ln1b,
      W1B1, W1B2, W2h, W2l, ffb1, ffb2, ln2g, ln2b,
      wqkv + 42 * 14, bqkv + 42,
      Qpack1, KB1_1, KB2_1, VhiT1, VloT1);

  layer1_tail<<<256, 512, 0, stream>>>(
      Qpack1, KB1_1, KB2_1, VhiT1, VloT1, h,
      wo + 196, bo + 14, ln1g + 14, ln1b + 14,
      W1B1 + (size_t)2048 * 16, W1B2 + (size_t)2048 * 16,
      W2h + (size_t)16 * FF, W2l + (size_t)16 * FF,
      ffb1 + FF, ffb2 + 14, ln2g + 14, ln2b + 14,
      fc1w, fc1b, fc2w, fc2b, x, y,
      B3h, B3l, fc3b, B4h, B4l, fc4b,
      fc5w, fc5b, out, out + NN);
}

// Round 8
// 232.304 us; speedup vs baseline: 1.2313x; 1.0097x over previous
//
#include <hip/hip_runtime.h>
#include <math.h>

#define NN 8192
#define DD 14
#define DP 16
#define FF 2048
#define HID 256
#define LN_EPS 1e-5f
#define QSCALE (1.4426950408889634f / 3.7416573867739413f)  // log2(e)/sqrt(14)

typedef short bf16x8 __attribute__((ext_vector_type(8)));
typedef float f32x4 __attribute__((ext_vector_type(4)));

#define LOAD16(dst, srcp) { \
  const float4* _p = (const float4*)(srcp); \
  float4 _a = _p[0], _b = _p[1], _c = _p[2], _d = _p[3]; \
  dst[0]=_a.x; dst[1]=_a.y; dst[2]=_a.z; dst[3]=_a.w; \
  dst[4]=_b.x; dst[5]=_b.y; dst[6]=_b.z; dst[7]=_b.w; \
  dst[8]=_c.x; dst[9]=_c.y; dst[10]=_c.z; dst[11]=_c.w; \
  dst[12]=_d.x; dst[13]=_d.y; dst[14]=_d.z; dst[15]=_d.w; }

#define STORE16(dstp, src) { \
  float4* _p = (float4*)(dstp); \
  _p[0] = make_float4(src[0], src[1], src[2], src[3]); \
  _p[1] = make_float4(src[4], src[5], src[6], src[7]); \
  _p[2] = make_float4(src[8], src[9], src[10], src[11]); \
  _p[3] = make_float4(src[12], src[13], src[14], src[15]); }

static __device__ __forceinline__ float fast_exp2(float x) {
#if __has_builtin(__builtin_amdgcn_exp2f)
  return __builtin_amdgcn_exp2f(x);
#else
  return exp2f(x);
#endif
}

static __device__ __forceinline__ unsigned short bf_hi(float x) {
  return (unsigned short)(__float_as_uint(x) >> 16);
}
static __device__ __forceinline__ float bf_hi_f(float x) {
  return __uint_as_float(__float_as_uint(x) & 0xffff0000u);
}

// ---- repack 8 floats -> bf16 hi/lo fragments ----
static __device__ __forceinline__ void split8(const float* pv, bf16x8* ph, bf16x8* pl) {
  #pragma unroll
  for (int i = 0; i < 8; i++) {
    unsigned int u = __float_as_uint(pv[i]);
    (*ph)[i] = (short)(u >> 16);
    float rr = pv[i] - __uint_as_float(u & 0xffff0000u);
    (*pl)[i] = (short)(__float_as_uint(rr) >> 16);
  }
}

// ---- shared helper: compute qkv for row r from hr[16], store packed operands ----
static __device__ __forceinline__ void qkv_compute_store(
    int r, const float* hr, const float* __restrict__ wqkv,
    const float* __restrict__ bqkv, unsigned int* __restrict__ Qpack,
    unsigned int* __restrict__ KB1, unsigned int* __restrict__ KB2,
    unsigned short* __restrict__ VhiT, unsigned short* __restrict__ VloT) {
  float q[14], k[14], v[14];
  #pragma unroll 6
  for (int c = 0; c < 42; c++) {
    const float* w = wqkv + c * 14;
    float s = bqkv[c];
    #pragma unroll
    for (int d = 0; d < 14; d++) s = fmaf(hr[d], w[d], s);
    if (c < 14)       q[c] = s * QSCALE;
    else if (c < 28)  k[c - 14] = s;
    else              v[c - 28] = s;
  }
  unsigned int qp[16], k1[16], k2[16];
  unsigned short qh[14], ql[14], kh[14], kl[14];
  #pragma unroll
  for (int d = 0; d < 14; d++) {
    qh[d] = bf_hi(q[d]);
    ql[d] = bf_hi(q[d] - bf_hi_f(q[d]));
    kh[d] = bf_hi(k[d]);
    kl[d] = bf_hi(k[d] - bf_hi_f(k[d]));
  }
  #pragma unroll
  for (int i = 0; i < 7; i++) {
    qp[i]     = (unsigned int)qh[2*i] | ((unsigned int)qh[2*i+1] << 16);
    qp[8 + i] = (unsigned int)ql[2*i] | ((unsigned int)ql[2*i+1] << 16);
    k1[i]     = (unsigned int)kh[2*i] | ((unsigned int)kh[2*i+1] << 16);
    k1[8 + i] = k1[i];
    k2[i]     = (unsigned int)kl[2*i] | ((unsigned int)kl[2*i+1] << 16);
    k2[8 + i] = k2[i];
  }
  qp[7] = 0; qp[15] = 0; k1[7] = 0; k1[15] = 0; k2[7] = 0; k2[15] = 0;
  uint4* Qp4 = (uint4*)(Qpack + (size_t)r * 16);
  uint4* K14 = (uint4*)(KB1 + (size_t)r * 16);
  uint4* K24 = (uint4*)(KB2 + (size_t)r * 16);
  #pragma unroll
  for (int i = 0; i < 4; i++) {
    Qp4[i] = make_uint4(qp[4*i], qp[4*i+1], qp[4*i+2], qp[4*i+3]);
    K14[i] = make_uint4(k1[4*i], k1[4*i+1], k1[4*i+2], k1[4*i+3]);
    K24[i] = make_uint4(k2[4*i], k2[4*i+1], k2[4*i+2], k2[4*i+3]);
  }
  #pragma unroll
  for (int d = 0; d < 14; d++) {
    VhiT[(size_t)d * NN + r] = bf_hi(v[d]);
    VloT[(size_t)d * NN + r] = bf_hi(v[d] - bf_hi_f(v[d]));
  }
  VhiT[(size_t)14 * NN + r] = 0x3F80;  // ones column = softmax denom
  VhiT[(size_t)15 * NN + r] = 0;
  VloT[(size_t)14 * NN + r] = 0;
  VloT[(size_t)15 * NN + r] = 0;
}

// ---- shared helper: A-operand pack of 14-dim vector (hi|lo) ----
static __device__ __forceinline__ void store_apack(unsigned int* dst, const float* o) {
  unsigned int qp[16];
  unsigned short hh[14], ll[14];
  #pragma unroll
  for (int d = 0; d < 14; d++) {
    hh[d] = bf_hi(o[d]);
    ll[d] = bf_hi(o[d] - bf_hi_f(o[d]));
  }
  #pragma unroll
  for (int i = 0; i < 7; i++) {
    qp[i]     = (unsigned int)hh[2*i] | ((unsigned int)hh[2*i+1] << 16);
    qp[8 + i] = (unsigned int)ll[2*i] | ((unsigned int)ll[2*i+1] << 16);
  }
  qp[7] = 0; qp[15] = 0;
  uint4* d4 = (uint4*)dst;
  #pragma unroll
  for (int i = 0; i < 4; i++)
    d4[i] = make_uint4(qp[4*i], qp[4*i+1], qp[4*i+2], qp[4*i+3]);
}

// ---- combine + LN (out-proj variant) ----
static __device__ __forceinline__ void combine_ln1(
    const float* srow, const float* hr, const float* __restrict__ wo,
    const float* __restrict__ bo, const float* __restrict__ g,
    const float* __restrict__ b, float* o) {
  float L = srow[14];
  float inv = 1.f / L;
  float a[14];
  #pragma unroll
  for (int d = 0; d < 14; d++) a[d] = srow[d] * inv;
  float xx[14];
  #pragma unroll
  for (int i = 0; i < 14; i++) {
    float s = bo[i];
    #pragma unroll
    for (int d = 0; d < 14; d++) s = fmaf(wo[i * 14 + d], a[d], s);
    xx[i] = hr[i] + s;
  }
  float mu = 0.f;
  #pragma unroll
  for (int i = 0; i < 14; i++) mu += xx[i];
  mu *= (1.f / 14.f);
  float var = 0.f;
  #pragma unroll
  for (int i = 0; i < 14; i++) { float tt = xx[i] - mu; var = fmaf(tt, tt, var); }
  var *= (1.f / 14.f);
  float rs = rsqrtf(var + LN_EPS);
  #pragma unroll
  for (int i = 0; i < 14; i++) o[i] = fmaf((xx[i] - mu) * rs, g[i], b[i]);
  o[14] = 0.f; o[15] = 0.f;
}

// ======================================================================
// K1: weight packs (fc3/fc4/ffn) + layer-0 qkv from x  (unchanged, proven)
// ======================================================================
__global__ void pack_all(const float* __restrict__ w3, const float* __restrict__ w4,
                         const float* __restrict__ ffw1, const float* __restrict__ ffw2,
                         const float* __restrict__ x, const float* __restrict__ wqkv,
                         const float* __restrict__ bqkv, float* __restrict__ h,
                         unsigned int* __restrict__ Qpack,
                         unsigned int* __restrict__ KB1, unsigned int* __restrict__ KB2,
                         unsigned short* __restrict__ VhiT, unsigned short* __restrict__ VloT,
                         unsigned short* __restrict__ B3h, unsigned short* __restrict__ B3l,
                         unsigned short* __restrict__ B4h, unsigned short* __restrict__ B4l,
                         unsigned int* __restrict__ W1B1, unsigned int* __restrict__ W1B2,
                         unsigned short* __restrict__ W2h, unsigned short* __restrict__ W2l) {
  const int blk = blockIdx.x, tid = threadIdx.x;
  if (blk < 32) {
    int t = blk * 256 + tid;
    int lane = t & 63, ks = (t >> 6) & 7, nt = t >> 9;
    int n = nt * 16 + (lane & 15);
    int k0 = ks * 32 + (lane >> 4) * 8;
    unsigned int h4[4], l4[4];
    #pragma unroll
    for (int jj = 0; jj < 4; jj++) {
      unsigned short h2[2], l2[2];
      #pragma unroll
      for (int e = 0; e < 2; e++) {
        float v = w4[(size_t)n * 256 + k0 + jj * 2 + e];
        h2[e] = bf_hi(v);
        l2[e] = bf_hi(v - bf_hi_f(v));
      }
      h4[jj] = (unsigned int)h2[0] | ((unsigned int)h2[1] << 16);
      l4[jj] = (unsigned int)l2[0] | ((unsigned int)l2[1] << 16);
    }
    ((uint4*)B4h)[t] = make_uint4(h4[0], h4[1], h4[2], h4[3]);
    ((uint4*)B4l)[t] = make_uint4(l4[0], l4[1], l4[2], l4[3]);
    if (ks < 2) {
      int fi = (nt * 2 + ks) * 64 + lane;
      #pragma unroll
      for (int jj = 0; jj < 4; jj++) {
        unsigned short h2[2], l2[2];
        #pragma unroll
        for (int e = 0; e < 2; e++) {
          int k = k0 + jj * 2 + e;
          float v = (k < 51) ? w3[(size_t)n * 51 + k] : 0.f;
          h2[e] = bf_hi(v);
          l2[e] = bf_hi(v - bf_hi_f(v));
        }
        h4[jj] = (unsigned int)h2[0] | ((unsigned int)h2[1] << 16);
        l4[jj] = (unsigned int)l2[0] | ((unsigned int)l2[1] << 16);
      }
      ((uint4*)B3h)[fi] = make_uint4(h4[0], h4[1], h4[2], h4[3]);
      ((uint4*)B3l)[fi] = make_uint4(l4[0], l4[1], l4[2], l4[3]);
    }
  } else if (blk < 48) {
    int t = (blk - 32) * 256 + tid;
    int l = t >> 11, j = t & 2047;
    const float* wrow = ffw1 + ((size_t)l * FF + j) * 14;
    unsigned int k1[16], k2[16];
    unsigned short kh[14], kl[14];
    #pragma unroll
    for (int d = 0; d < 14; d++) {
      float v = wrow[d];
      kh[d] = bf_hi(v);
      kl[d] = bf_hi(v - bf_hi_f(v));
    }
    #pragma unroll
    for (int i = 0; i < 7; i++) {
      k1[i] = (unsigned int)kh[2*i] | ((unsigned int)kh[2*i+1] << 16);
      k1[8 + i] = k1[i];
      k2[i] = (unsigned int)kl[2*i] | ((unsigned int)kl[2*i+1] << 16);
      k2[8 + i] = k2[i];
    }
    k1[7] = 0; k1[15] = 0; k2[7] = 0; k2[15] = 0;
    uint4* d1 = (uint4*)(W1B1 + (size_t)t * 16);
    uint4* d2 = (uint4*)(W1B2 + (size_t)t * 16);
    #pragma unroll
    for (int i = 0; i < 4; i++) {
      d1[i] = make_uint4(k1[4*i], k1[4*i+1], k1[4*i+2], k1[4*i+3]);
      d2[i] = make_uint4(k2[4*i], k2[4*i+1], k2[4*i+2], k2[4*i+3]);
    }
  } else if (blk < 64) {
    int t = (blk - 48) * 256 + tid;
    int l = t >> 11, j = t & 2047;
    #pragma unroll
    for (int d = 0; d < 16; d++) {
      float v = (d < 14) ? ffw2[((size_t)l * 14 + d) * FF + j] : 0.f;
      W2h[((size_t)l * 16 + d) * FF + j] = bf_hi(v);
      W2l[((size_t)l * 16 + d) * FF + j] = bf_hi(v - bf_hi_f(v));
    }
  } else {
    int r = (blk - 64) * 256 + tid;
    float hr[16];
    #pragma unroll
    for (int d = 0; d < 14; d++) hr[d] = x[(size_t)r * 14 + d];
    hr[14] = 0.f; hr[15] = 0.f;
    STORE16(h + (size_t)r * DP, hr);
    qkv_compute_store(r, hr, wqkv, bqkv, Qpack, KB1, KB2, VhiT, VloT);
  }
}

// ======================================================================
// Pipelined 32-row attention core (r4-proven body, chunk count templated):
// LDS reads of P(c-1) issued before writes of P(c); per-wave DS order
// guarantees old data.  Wave covers NCHUNK*32 keys starting at kstart.
// ======================================================================
template<int NCHUNK>
static __device__ __forceinline__ void attn_core(
    const bf16x8* __restrict__ Qp, const bf16x8* __restrict__ B1,
    const bf16x8* __restrict__ B2, const bf16x8* __restrict__ Vh,
    const bf16x8* __restrict__ Vl, int qbase, int kstart, int lo4, int hi4,
    float (*Pl)[36], f32x4* o0, f32x4* o1) {
  const f32x4 zero = {0.f, 0.f, 0.f, 0.f};
  bf16x8 aQ0 = Qp[(size_t)(qbase + lo4) * 4 + hi4];
  bf16x8 aQ1 = Qp[(size_t)(qbase + 16 + lo4) * 4 + hi4];
  f32x4 acc0 = zero, acc1 = zero;
  float4 ra0, ra1, rc0, rc1;
  const float4* p0 = (const float4*)&Pl[lo4][hi4 * 8];
  const float4* p1 = (const float4*)&Pl[16 + lo4][hi4 * 8];

  for (int c = 0; c < NCHUNK; c++) {
    const int kb = kstart + c * 32;
    if (c > 0) {            // issue reads of P(c-1) early
      ra0 = p0[0]; ra1 = p0[1]; rc0 = p1[0]; rc1 = p1[1];
      __asm__ volatile("" ::: "memory");   // keep reads above the writes below
    }
    bf16x8 b1g0 = B1[(size_t)(kb + lo4) * 4 + hi4];
    bf16x8 b2g0 = B2[(size_t)(kb + lo4) * 4 + hi4];
    bf16x8 b1g1 = B1[(size_t)(kb + 16 + lo4) * 4 + hi4];
    bf16x8 b2g1 = B2[(size_t)(kb + 16 + lo4) * 4 + hi4];
    bf16x8 vh = Vh[(size_t)lo4 * 1024 + (kb >> 3) + hi4];
    bf16x8 vl = Vl[(size_t)lo4 * 1024 + (kb >> 3) + hi4];

    f32x4 s00 = __builtin_amdgcn_mfma_f32_16x16x32_bf16(aQ0, b1g0, zero, 0, 0, 0);
    f32x4 s01 = __builtin_amdgcn_mfma_f32_16x16x32_bf16(aQ0, b1g1, zero, 0, 0, 0);
    f32x4 s10 = __builtin_amdgcn_mfma_f32_16x16x32_bf16(aQ1, b1g0, zero, 0, 0, 0);
    f32x4 s11 = __builtin_amdgcn_mfma_f32_16x16x32_bf16(aQ1, b1g1, zero, 0, 0, 0);
    s00 = __builtin_amdgcn_mfma_f32_16x16x32_bf16(aQ0, b2g0, s00, 0, 0, 0);
    s01 = __builtin_amdgcn_mfma_f32_16x16x32_bf16(aQ0, b2g1, s01, 0, 0, 0);
    s10 = __builtin_amdgcn_mfma_f32_16x16x32_bf16(aQ1, b2g0, s10, 0, 0, 0);
    s11 = __builtin_amdgcn_mfma_f32_16x16x32_bf16(aQ1, b2g1, s11, 0, 0, 0);
    // write P(c) (queued after the early reads -> reads return old data)
    #pragma unroll
    for (int reg = 0; reg < 4; reg++) {
      Pl[hi4 * 4 + reg][lo4]           = fast_exp2(s00[reg]);
      Pl[hi4 * 4 + reg][16 + lo4]      = fast_exp2(s01[reg]);
      Pl[16 + hi4 * 4 + reg][lo4]      = fast_exp2(s10[reg]);
      Pl[16 + hi4 * 4 + reg][16 + lo4] = fast_exp2(s11[reg]);
    }
    if (c > 0) {            // PV of chunk c-1
      const int kbp = kb - 32;
      bf16x8 vhp = Vh[(size_t)lo4 * 1024 + (kbp >> 3) + hi4];
      bf16x8 vlp = Vl[(size_t)lo4 * 1024 + (kbp >> 3) + hi4];
      float pv0[8] = {ra0.x, ra0.y, ra0.z, ra0.w, ra1.x, ra1.y, ra1.z, ra1.w};
      float pv1[8] = {rc0.x, rc0.y, rc0.z, rc0.w, rc1.x, rc1.y, rc1.z, rc1.w};
      bf16x8 ph0, pl0, ph1, pl1;
      split8(pv0, &ph0, &pl0);
      split8(pv1, &ph1, &pl1);
      acc0 = __builtin_amdgcn_mfma_f32_16x16x32_bf16(ph0, vhp, acc0, 0, 0, 0);
      acc1 = __builtin_amdgcn_mfma_f32_16x16x32_bf16(ph1, vhp, acc1, 0, 0, 0);
      acc0 = __builtin_amdgcn_mfma_f32_16x16x32_bf16(pl0, vhp, acc0, 0, 0, 0);
      acc1 = __builtin_amdgcn_mfma_f32_16x16x32_bf16(pl1, vhp, acc1, 0, 0, 0);
      acc0 = __builtin_amdgcn_mfma_f32_16x16x32_bf16(ph0, vlp, acc0, 0, 0, 0);
      acc1 = __builtin_amdgcn_mfma_f32_16x16x32_bf16(ph1, vlp, acc1, 0, 0, 0);
    }
  }
  // epilogue: PV of last chunk
  {
    const int kbp = kstart + (NCHUNK - 1) * 32;
    bf16x8 vhp = Vh[(size_t)lo4 * 1024 + (kbp >> 3) + hi4];
    bf16x8 vlp = Vl[(size_t)lo4 * 1024 + (kbp >> 3) + hi4];
    float4 a0 = p0[0], a1 = p0[1], c0 = p1[0], c1 = p1[1];
    float pv0[8] = {a0.x, a0.y, a0.z, a0.w, a1.x, a1.y, a1.z, a1.w};
    float pv1[8] = {c0.x, c0.y, c0.z, c0.w, c1.x, c1.y, c1.z, c1.w};
    bf16x8 ph0, pl0, ph1, pl1;
    split8(pv0, &ph0, &pl0);
    split8(pv1, &ph1, &pl1);
    acc0 = __builtin_amdgcn_mfma_f32_16x16x32_bf16(ph0, vhp, acc0, 0, 0, 0);
    acc1 = __builtin_amdgcn_mfma_f32_16x16x32_bf16(ph1, vhp, acc1, 0, 0, 0);
    acc0 = __builtin_amdgcn_mfma_f32_16x16x32_bf16(pl0, vhp, acc0, 0, 0, 0);
    acc1 = __builtin_amdgcn_mfma_f32_16x16x32_bf16(pl1, vhp, acc1, 0, 0, 0);
    acc0 = __builtin_amdgcn_mfma_f32_16x16x32_bf16(ph0, vlp, acc0, 0, 0, 0);
    acc1 = __builtin_amdgcn_mfma_f32_16x16x32_bf16(ph1, vlp, acc1, 0, 0, 0);
  }
  *o0 = acc0; *o1 = acc1;
}

// ======================================================================
// Pipelined 32-row FFN core (r4-proven body, chunk count templated).
// ======================================================================
template<int NCHUNK>
static __device__ __forceinline__ void ffn_core(
    bf16x8 aH0, bf16x8 aH1, const bf16x8* __restrict__ B1,
    const bf16x8* __restrict__ B2, const bf16x8* __restrict__ Vh,
    const bf16x8* __restrict__ Vl, const float* __restrict__ b1,
    int jstart, int lo4, int hi4, float (*Pl)[36], f32x4* o0, f32x4* o1) {
  const f32x4 zero = {0.f, 0.f, 0.f, 0.f};
  f32x4 acc0 = zero, acc1 = zero;
  float4 ra0, ra1, rc0, rc1;
  const float4* p0 = (const float4*)&Pl[lo4][hi4 * 8];
  const float4* p1 = (const float4*)&Pl[16 + lo4][hi4 * 8];

  for (int c = 0; c < NCHUNK; c++) {
    const int jb = jstart + c * 32;
    if (c > 0) {
      ra0 = p0[0]; ra1 = p0[1]; rc0 = p1[0]; rc1 = p1[1];
      __asm__ volatile("" ::: "memory");
    }
    bf16x8 b1g0 = B1[(size_t)(jb + lo4) * 4 + hi4];
    bf16x8 b2g0 = B2[(size_t)(jb + lo4) * 4 + hi4];
    bf16x8 b1g1 = B1[(size_t)(jb + 16 + lo4) * 4 + hi4];
    bf16x8 b2g1 = B2[(size_t)(jb + 16 + lo4) * 4 + hi4];
    float bb0 = b1[jb + lo4];
    float bb1 = b1[jb + 16 + lo4];

    f32x4 s00 = __builtin_amdgcn_mfma_f32_16x16x32_bf16(aH0, b1g0, zero, 0, 0, 0);
    f32x4 s01 = __builtin_amdgcn_mfma_f32_16x16x32_bf16(aH0, b1g1, zero, 0, 0, 0);
    f32x4 s10 = __builtin_amdgcn_mfma_f32_16x16x32_bf16(aH1, b1g0, zero, 0, 0, 0);
    f32x4 s11 = __builtin_amdgcn_mfma_f32_16x16x32_bf16(aH1, b1g1, zero, 0, 0, 0);
    s00 = __builtin_amdgcn_mfma_f32_16x16x32_bf16(aH0, b2g0, s00, 0, 0, 0);
    s01 = __builtin_amdgcn_mfma_f32_16x16x32_bf16(aH0, b2g1, s01, 0, 0, 0);
    s10 = __builtin_amdgcn_mfma_f32_16x16x32_bf16(aH1, b2g0, s10, 0, 0, 0);
    s11 = __builtin_amdgcn_mfma_f32_16x16x32_bf16(aH1, b2g1, s11, 0, 0, 0);
    #pragma unroll
    for (int reg = 0; reg < 4; reg++) {
      Pl[hi4 * 4 + reg][lo4]           = fmaxf(s00[reg] + bb0, 0.f);
      Pl[hi4 * 4 + reg][16 + lo4]      = fmaxf(s01[reg] + bb1, 0.f);
      Pl[16 + hi4 * 4 + reg][lo4]      = fmaxf(s10[reg] + bb0, 0.f);
      Pl[16 + hi4 * 4 + reg][16 + lo4] = fmaxf(s11[reg] + bb1, 0.f);
    }
    if (c > 0) {
      const int jbp = jb - 32;
      bf16x8 vhp = Vh[(size_t)lo4 * 256 + (jbp >> 3) + hi4];
      bf16x8 vlp = Vl[(size_t)lo4 * 256 + (jbp >> 3) + hi4];
      float pv0[8] = {ra0.x, ra0.y, ra0.z, ra0.w, ra1.x, ra1.y, ra1.z, ra1.w};
      float pv1[8] = {rc0.x, rc0.y, rc0.z, rc0.w, rc1.x, rc1.y, rc1.z, rc1.w};
      bf16x8 th0, tl0, th1, tl1;
      split8(pv0, &th0, &tl0);
      split8(pv1, &th1, &tl1);
      acc0 = __builtin_amdgcn_mfma_f32_16x16x32_bf16(th0, vhp, acc0, 0, 0, 0);
      acc1 = __builtin_amdgcn_mfma_f32_16x16x32_bf16(th1, vhp, acc1, 0, 0, 0);
      acc0 = __builtin_amdgcn_mfma_f32_16x16x32_bf16(tl0, vhp, acc0, 0, 0, 0);
      acc1 = __builtin_amdgcn_mfma_f32_16x16x32_bf16(tl1, vhp, acc1, 0, 0, 0);
      acc0 = __builtin_amdgcn_mfma_f32_16x16x32_bf16(th0, vlp, acc0, 0, 0, 0);
      acc1 = __builtin_amdgcn_mfma_f32_16x16x32_bf16(th1, vlp, acc1, 0, 0, 0);
    }
  }
  {
    const int jbp = jstart + (NCHUNK - 1) * 32;
    bf16x8 vhp = Vh[(size_t)lo4 * 256 + (jbp >> 3) + hi4];
    bf16x8 vlp = Vl[(size_t)lo4 * 256 + (jbp >> 3) + hi4];
    float4 a0 = p0[0], a1 = p0[1], c0 = p1[0], c1 = p1[1];
    float pv0[8] = {a0.x, a0.y, a0.z, a0.w, a1.x, a1.y, a1.z, a1.w};
    float pv1[8] = {c0.x, c0.y, c0.z, c0.w, c1.x, c1.y, c1.z, c1.w};
    bf16x8 th0, tl0, th1, tl1;
    split8(pv0, &th0, &tl0);
    split8(pv1, &th1, &tl1);
    acc0 = __builtin_amdgcn_mfma_f32_16x16x32_bf16(th0, vhp, acc0, 0, 0, 0);
    acc1 = __builtin_amdgcn_mfma_f32_16x16x32_bf16(th1, vhp, acc1, 0, 0, 0);
    acc0 = __builtin_amdgcn_mfma_f32_16x16x32_bf16(tl0, vhp, acc0, 0, 0, 0);
    acc1 = __builtin_amdgcn_mfma_f32_16x16x32_bf16(tl1, vhp, acc1, 0, 0, 0);
    acc0 = __builtin_amdgcn_mfma_f32_16x16x32_bf16(th0, vlp, acc0, 0, 0, 0);
    acc1 = __builtin_amdgcn_mfma_f32_16x16x32_bf16(th1, vlp, acc1, 0, 0, 0);
  }
  *o0 = acc0; *o1 = acc1;
}

// LDS layout (bytes), 16-wave blocks, 32 rows/block — CORRECTED SIZES:
//  main : Pl   16 x [32][36] f32  :      0..73728   (4608 B per wave)
//         sacc [16][32][16] f32   :      0..32768   (ALIASES Pl; barrier first)
//         hrow [32][16] f32       :  73728..75776
//         Hl   [32][16] u32       :  75776..77824
//         szf  [32] f32           :  77824..77952
//  tail : Ah 2x[16][72] 0..4608 | Al 4608..9216 | R1h 9216..26112 |
//         R1l 26112..43008 | sred 2x[8][16][16] 43008..59392  (all < 73728)
#define SMEM_BYTES 77952

// ======================================================================
// K2: layer 0 = attn + LN1 + ffn + LN2 + layer-1 qkv pack.
// 256 blocks x 1024 threads (16 waves): wave covers 512 keys / 128 neurons.
// 1 block/CU (78 KB LDS) -> 16 waves/CU = 4 waves/SIMD, with the round-4
// per-wave chunk structure byte-identical.
// ======================================================================
__global__ __launch_bounds__(1024, 1) void layer0_fused(
    const unsigned int* __restrict__ Qpack, const unsigned int* __restrict__ KB1,
    const unsigned int* __restrict__ KB2, const unsigned short* __restrict__ VhiT,
    const unsigned short* __restrict__ VloT, float* __restrict__ h,
    const float* __restrict__ wo, const float* __restrict__ bo,
    const float* __restrict__ g1, const float* __restrict__ b1n,
    const unsigned int* __restrict__ W1B1, const unsigned int* __restrict__ W1B2,
    const unsigned short* __restrict__ W2h, const unsigned short* __restrict__ W2l,
    const float* __restrict__ fb1, const float* __restrict__ fb2,
    const float* __restrict__ g2, const float* __restrict__ b2n,
    const float* __restrict__ wqkv1, const float* __restrict__ bqkv1,
    unsigned int* __restrict__ Qpack1, unsigned int* __restrict__ KB1_1,
    unsigned int* __restrict__ KB2_1, unsigned short* __restrict__ VhiT1,
    unsigned short* __restrict__ VloT1) {
  __shared__ alignas(16) char smem[SMEM_BYTES];
  const int tid = threadIdx.x;
  const int wave = tid >> 6;
  const int lane = tid & 63;
  const int lo4 = lane & 15;
  const int hi4 = lane >> 4;
  const int qbase = blockIdx.x * 32;

  float (*Pl)[36] = (float(*)[36])(smem + wave * 4608);
  float (*sacc)[32][16] = (float(*)[32][16])(smem);          // aliases Pl
  float (*hrow)[16] = (float(*)[16])(smem + 73728);
  unsigned int (*Hl)[16] = (unsigned int(*)[16])(smem + 75776);

  // ---- phase A: attention (wave covers keys [wave*512, wave*512+512)) ----
  f32x4 a0, a1;
  attn_core<16>((const bf16x8*)Qpack, (const bf16x8*)KB1, (const bf16x8*)KB2,
                (const bf16x8*)VhiT, (const bf16x8*)VloT, qbase, wave * 512,
                lo4, hi4, Pl, &a0, &a1);
  __syncthreads();   // Pl dead everywhere -> safe to alias with sacc
  #pragma unroll
  for (int reg = 0; reg < 4; reg++) {
    sacc[wave][hi4 * 4 + reg][lo4] = a0[reg];
    sacc[wave][16 + hi4 * 4 + reg][lo4] = a1[reg];
  }
  __syncthreads();
  if (tid < 512) {
    int qq = tid >> 4, col = tid & 15;
    float v = 0.f;
    #pragma unroll
    for (int w = 0; w < 16; w++) v += sacc[w][qq][col];
    sacc[0][qq][col] = v;
  }
  __syncthreads();
  if (tid < 32) {
    int r = qbase + tid;
    float hr[16];
    LOAD16(hr, h + (size_t)r * DP);
    float o[16];
    combine_ln1(&sacc[0][tid][0], hr, wo, bo, g1, b1n, o);
    #pragma unroll
    for (int i = 0; i < 16; i++) hrow[tid][i] = o[i];
    store_apack(&Hl[tid][0], o);
  }
  __syncthreads();

  // ---- phase B: FFN (wave covers neurons [wave*128, wave*128+128)) ----
  bf16x8 aH0 = *(const bf16x8*)&Hl[lo4][hi4 * 4];
  bf16x8 aH1 = *(const bf16x8*)&Hl[16 + lo4][hi4 * 4];
  f32x4 f0, f1;
  ffn_core<4>(aH0, aH1, (const bf16x8*)W1B1, (const bf16x8*)W1B2,
              (const bf16x8*)W2h, (const bf16x8*)W2l, fb1, wave * 128,
              lo4, hi4, Pl, &f0, &f1);
  __syncthreads();   // Pl dead -> alias with sacc
  #pragma unroll
  for (int reg = 0; reg < 4; reg++) {
    sacc[wave][hi4 * 4 + reg][lo4] = f0[reg];
    sacc[wave][16 + hi4 * 4 + reg][lo4] = f1[reg];
  }
  __syncthreads();
  if (tid < 512) {
    int qq = tid >> 4, col = tid & 15;
    float v = 0.f;
    #pragma unroll
    for (int w = 0; w < 16; w++) v += sacc[w][qq][col];
    sacc[0][qq][col] = v;
  }
  __syncthreads();
  if (tid < 32) {
    int r = qbase + tid;
    float xx[14];
    #pragma unroll
    for (int i = 0; i < 14; i++) xx[i] = hrow[tid][i] + sacc[0][tid][i] + fb2[i];
    float mu = 0.f;
    #pragma unroll
    for (int i = 0; i < 14; i++) mu += xx[i];
    mu *= (1.f / 14.f);
    float var = 0.f;
    #pragma unroll
    for (int i = 0; i < 14; i++) { float tt = xx[i] - mu; var = fmaf(tt, tt, var); }
    var *= (1.f / 14.f);
    float rs = rsqrtf(var + LN_EPS);
    float o[16];
    #pragma unroll
    for (int i = 0; i < 14; i++) o[i] = fmaf((xx[i] - mu) * rs, g2[i], b2n[i]);
    o[14] = 0.f; o[15] = 0.f;
    STORE16(h + (size_t)r * DP, o);
    qkv_compute_store(r, o, wqkv1, bqkv1, Qpack1, KB1_1, KB2_1, VhiT1, VloT1);
  }
}

// ======================================================================
// K3: layer 1 = attn + LN1 + ffn + LN2 + size head + regression tail.
// 256 blocks x 1024 threads; tail: two 16-row groups x 8 waves x 2 tiles.
// ======================================================================
__global__ __launch_bounds__(1024, 1) void layer1_tail(
    const unsigned int* __restrict__ Qpack, const unsigned int* __restrict__ KB1,
    const unsigned int* __restrict__ KB2, const unsigned short* __restrict__ VhiT,
    const unsigned short* __restrict__ VloT, const float* __restrict__ h,
    const float* __restrict__ wo, const float* __restrict__ bo,
    const float* __restrict__ g1, const float* __restrict__ b1n,
    const unsigned int* __restrict__ W1B1, const unsigned int* __restrict__ W1B2,
    const unsigned short* __restrict__ W2h, const unsigned short* __restrict__ W2l,
    const float* __restrict__ fb1, const float* __restrict__ fb2,
    const float* __restrict__ g2, const float* __restrict__ b2n,
    const float* __restrict__ fc1w, const float* __restrict__ fc1b,
    const float* __restrict__ fc2w, const float* __restrict__ fc2b,
    const float* __restrict__ x, const float* __restrict__ y,
    const unsigned short* __restrict__ B3h, const unsigned short* __restrict__ B3l,
    const float* __restrict__ b3,
    const unsigned short* __restrict__ B4h, const unsigned short* __restrict__ B4l,
    const float* __restrict__ b4,
    const float* __restrict__ w5, const float* __restrict__ b5,
    float* __restrict__ out, float* __restrict__ outr) {
  __shared__ alignas(16) char smem[SMEM_BYTES];
  const int tid = threadIdx.x;
  const int wave = tid >> 6;
  const int lane = tid & 63;
  const int lo4 = lane & 15;
  const int hi4 = lane >> 4;
  const int qbase = blockIdx.x * 32;
  const f32x4 zero = {0.f, 0.f, 0.f, 0.f};

  float (*Pl)[36] = (float(*)[36])(smem + wave * 4608);
  float (*sacc)[32][16] = (float(*)[32][16])(smem);
  float (*hrow)[16] = (float(*)[16])(smem + 73728);
  unsigned int (*Hl)[16] = (unsigned int(*)[16])(smem + 75776);
  float* szf = (float*)(smem + 77824);

  // ---- phase A: attention (layer 1) ----
  f32x4 a0, a1;
  attn_core<16>((const bf16x8*)Qpack, (const bf16x8*)KB1, (const bf16x8*)KB2,
                (const bf16x8*)VhiT, (const bf16x8*)VloT, qbase, wave * 512,
                lo4, hi4, Pl, &a0, &a1);
  __syncthreads();
  #pragma unroll
  for (int reg = 0; reg < 4; reg++) {
    sacc[wave][hi4 * 4 + reg][lo4] = a0[reg];
    sacc[wave][16 + hi4 * 4 + reg][lo4] = a1[reg];
  }
  __syncthreads();
  if (tid < 512) {
    int qq = tid >> 4, col = tid & 15;
    float v = 0.f;
    #pragma unroll
    for (int w = 0; w < 16; w++) v += sacc[w][qq][col];
    sacc[0][qq][col] = v;
  }
  __syncthreads();
  if (tid < 32) {
    int r = qbase + tid;
    float hr[16];
    LOAD16(hr, h + (size_t)r * DP);
    float o[16];
    combine_ln1(&sacc[0][tid][0], hr, wo, bo, g1, b1n, o);
    #pragma unroll
    for (int i = 0; i < 16; i++) hrow[tid][i] = o[i];
    store_apack(&Hl[tid][0], o);
  }
  __syncthreads();

  // ---- phase B: FFN (layer 1) + LN2 + size head ----
  bf16x8 aH0 = *(const bf16x8*)&Hl[lo4][hi4 * 4];
  bf16x8 aH1 = *(const bf16x8*)&Hl[16 + lo4][hi4 * 4];
  f32x4 f0, f1;
  ffn_core<4>(aH0, aH1, (const bf16x8*)W1B1, (const bf16x8*)W1B2,
              (const bf16x8*)W2h, (const bf16x8*)W2l, fb1, wave * 128,
              lo4, hi4, Pl, &f0, &f1);
  __syncthreads();
  #pragma unroll
  for (int reg = 0; reg < 4; reg++) {
    sacc[wave][hi4 * 4 + reg][lo4] = f0[reg];
    sacc[wave][16 + hi4 * 4 + reg][lo4] = f1[reg];
  }
  __syncthreads();
  if (tid < 512) {
    int qq = tid >> 4, col = tid & 15;
    float v = 0.f;
    #pragma unroll
    for (int w = 0; w < 16; w++) v += sacc[w][qq][col];
    sacc[0][qq][col] = v;
  }
  __syncthreads();
  if (tid < 32) {
    int r = qbase + tid;
    float xx[14];
    #pragma unroll
    for (int i = 0; i < 14; i++) xx[i] = hrow[tid][i] + sacc[0][tid][i] + fb2[i];
    float mu = 0.f;
    #pragma unroll
    for (int i = 0; i < 14; i++) mu += xx[i];
    mu *= (1.f / 14.f);
    float var = 0.f;
    #pragma unroll
    for (int i = 0; i < 14; i++) { float tt = xx[i] - mu; var = fmaf(tt, tt, var); }
    var *= (1.f / 14.f);
    float rs = rsqrtf(var + LN_EPS);
    float o[14];
    #pragma unroll
    for (int i = 0; i < 14; i++) o[i] = fmaf((xx[i] - mu) * rs, g2[i], b2n[i]);
    float s = fc2b[0];
    #pragma unroll
    for (int i = 0; i < 14; i++) {
      float tt = fc1b[i];
      #pragma unroll
      for (int d = 0; d < 14; d++) tt = fmaf(fc1w[i * 14 + d], o[d], tt);
      s = fmaf(tt, fc2w[i], s);
    }
    out[r] = s;
    int si = (int)s;  // trunc toward zero, matches astype(int32)
    szf[tid] = (float)si;
  }
  __syncthreads();

  // ---- phase C: regression head, two 16-row groups x 8 waves x 2 tiles ----
  const int grp = wave >> 3;   // 0 or 1: rows [qbase+grp*16, +16)
  const int wg  = wave & 7;    // wave-in-group 0..7

  for (int idx = tid; idx < 2 * 16 * 64; idx += 1024) {
    int g = idx >> 10, m = (idx >> 6) & 15, k = idx & 63;
    int r = qbase + g * 16 + m;
    float v = 0.f;
    if (k == 0)       v = szf[g * 16 + m];
    else if (k < 15)  v = x[(size_t)r * 14 + (k - 1)];
    else if (k < 51)  v = y[(size_t)r * 36 + (k - 15)];
    ((unsigned short(*)[72])(smem + g * 2304))[m][k] = bf_hi(v);
    ((unsigned short(*)[72])(smem + 4608 + g * 2304))[m][k] = bf_hi(v - bf_hi_f(v));
  }
  __syncthreads();

  unsigned short (*Ah)[72]  = (unsigned short(*)[72])(smem + grp * 2304);
  unsigned short (*Al)[72]  = (unsigned short(*)[72])(smem + 4608 + grp * 2304);
  unsigned short (*R1h)[264] = (unsigned short(*)[264])(smem + 9216 + grp * 8448);
  unsigned short (*R1l)[264] = (unsigned short(*)[264])(smem + 26112 + grp * 8448);
  float (*sred)[16][16] = (float(*)[16][16])(smem + 43008 + (size_t)grp * 8192);

  f32x4 acc[2];
  #pragma unroll
  for (int nt = 0; nt < 2; nt++) acc[nt] = zero;
  #pragma unroll
  for (int ks = 0; ks < 2; ks++) {
    bf16x8 ah = *(const bf16x8*)&Ah[lo4][ks * 32 + hi4 * 8];
    bf16x8 al = *(const bf16x8*)&Al[lo4][ks * 32 + hi4 * 8];
    #pragma unroll
    for (int nt = 0; nt < 2; nt++) {
      int fi = ((wg * 2 + nt) * 2 + ks) * 64 + lane;
      bf16x8 bh = ((const bf16x8*)B3h)[fi];
      bf16x8 bl = ((const bf16x8*)B3l)[fi];
      acc[nt] = __builtin_amdgcn_mfma_f32_16x16x32_bf16(ah, bh, acc[nt], 0, 0, 0);
      acc[nt] = __builtin_amdgcn_mfma_f32_16x16x32_bf16(al, bh, acc[nt], 0, 0, 0);
      acc[nt] = __builtin_amdgcn_mfma_f32_16x16x32_bf16(ah, bl, acc[nt], 0, 0, 0);
    }
  }
  #pragma unroll
  for (int nt = 0; nt < 2; nt++) {
    int n = (wg * 2 + nt) * 16 + lo4;
    float bbv = b3[n];
    #pragma unroll
    for (int reg = 0; reg < 4; reg++) {
      int m = hi4 * 4 + reg;
      float v = fmaxf(acc[nt][reg] + bbv, 0.f);
      R1h[m][n] = bf_hi(v);
      R1l[m][n] = bf_hi(v - bf_hi_f(v));
    }
  }
  __syncthreads();

  #pragma unroll
  for (int nt = 0; nt < 2; nt++) acc[nt] = zero;
  #pragma unroll
  for (int ks = 0; ks < 8; ks++) {
    bf16x8 ah = *(const bf16x8*)&R1h[lo4][ks * 32 + hi4 * 8];
    bf16x8 al = *(const bf16x8*)&R1l[lo4][ks * 32 + hi4 * 8];
    #pragma unroll
    for (int nt = 0; nt < 2; nt++) {
      int fi = ((wg * 2 + nt) * 8 + ks) * 64 + lane;
      bf16x8 bh = ((const bf16x8*)B4h)[fi];
      bf16x8 bl = ((const bf16x8*)B4l)[fi];
      acc[nt] = __builtin_amdgcn_mfma_f32_16x16x32_bf16(ah, bh, acc[nt], 0, 0, 0);
      acc[nt] = __builtin_amdgcn_mfma_f32_16x16x32_bf16(al, bh, acc[nt], 0, 0, 0);
      acc[nt] = __builtin_amdgcn_mfma_f32_16x16x32_bf16(ah, bl, acc[nt], 0, 0, 0);
    }
  }
  float s4[4] = {0.f, 0.f, 0.f, 0.f};
  #pragma unroll
  for (int nt = 0; nt < 2; nt++) {
    int n = (wg * 2 + nt) * 16 + lo4;
    float bbv = b4[n], ww = w5[n];
    #pragma unroll
    for (int reg = 0; reg < 4; reg++)
      s4[reg] = fmaf(fmaxf(acc[nt][reg] + bbv, 0.f), ww, s4[reg]);
  }
  #pragma unroll
  for (int reg = 0; reg < 4; reg++) sred[wg][hi4 * 4 + reg][lo4] = s4[reg];
  __syncthreads();

  if (tid < 32) {
    int g = tid >> 4, m = tid & 15;
    float (*sredG)[16][16] = (float(*)[16][16])(smem + 43008 + (size_t)g * 8192);
    float t = b5[0];
    #pragma unroll
    for (int w = 0; w < 8; w++) {
      const float4* p = (const float4*)&sredG[w][m][0];
      float4 q0 = p[0], q1 = p[1], q2 = p[2], q3 = p[3];
      t += ((q0.x + q0.y) + (q0.z + q0.w)) + ((q1.x + q1.y) + (q1.z + q1.w)) +
           ((q2.x + q2.y) + (q2.z + q2.w)) + ((q3.x + q3.y) + (q3.z + q3.w));
    }
    float sz = szf[tid];
    outr[qbase + tid] = (sz != 0.f) ? t : 0.f;
  }
}

extern "C" void kernel_launch(void* const* d_in, const int* in_sizes, int n_in,
                              void* d_out, int out_size, void* d_ws, size_t ws_size,
                              hipStream_t stream) {
  const float* x    = (const float*)d_in[0];
  const float* y    = (const float*)d_in[1];
  const float* wqkv = (const float*)d_in[2];
  const float* bqkv = (const float*)d_in[3];
  const float* wo   = (const float*)d_in[4];
  const float* bo   = (const float*)d_in[5];
  const float* ln1g = (const float*)d_in[6];
  const float* ln1b = (const float*)d_in[7];
  const float* ffw1 = (const float*)d_in[8];
  const float* ffb1 = (const float*)d_in[9];
  const float* ffw2 = (const float*)d_in[10];
  const float* ffb2 = (const float*)d_in[11];
  const float* ln2g = (const float*)d_in[12];
  const float* ln2b = (const float*)d_in[13];
  const float* fc1w = (const float*)d_in[14];
  const float* fc1b = (const float*)d_in[15];
  const float* fc2w = (const float*)d_in[16];
  const float* fc2b = (const float*)d_in[17];
  const float* fc3w = (const float*)d_in[18];
  const float* fc3b = (const float*)d_in[19];
  const float* fc4w = (const float*)d_in[20];
  const float* fc4b = (const float*)d_in[21];
  const float* fc5w = (const float*)d_in[22];
  const float* fc5b = (const float*)d_in[23];

  float* ws = (float*)d_ws;
  float*          h      = ws;                               // 131072 f
  unsigned int*   Qpack0 = (unsigned int*)(ws + 131072);
  unsigned int*   KB1_0  = (unsigned int*)(ws + 262144);
  unsigned int*   KB2_0  = (unsigned int*)(ws + 393216);
  unsigned short* VhiT0  = (unsigned short*)(ws + 524288);
  unsigned short* VloT0  = (unsigned short*)(ws + 589824);
  unsigned int*   Qpack1 = (unsigned int*)(ws + 786432);
  unsigned int*   KB1_1  = (unsigned int*)(ws + 917504);
  unsigned int*   KB2_1  = (unsigned int*)(ws + 1048576);
  unsigned short* VhiT1  = (unsigned short*)(ws + 1179648);
  unsigned short* VloT1  = (unsigned short*)(ws + 1245184);
  unsigned short* B3h    = (unsigned short*)(ws + 2891776);
  unsigned short* B3l    = (unsigned short*)(ws + 2899968);
  unsigned short* B4h    = (unsigned short*)(ws + 2908160);
  unsigned short* B4l    = (unsigned short*)(ws + 2940928);
  unsigned int*   W1B1   = (unsigned int*)(ws + 2973696);
  unsigned int*   W1B2   = (unsigned int*)(ws + 3039232);
  unsigned short* W2h    = (unsigned short*)(ws + 3104768);
  unsigned short* W2l    = (unsigned short*)(ws + 3137536);

  float* out = (float*)d_out;

  pack_all<<<96, 256, 0, stream>>>(fc3w, fc4w, ffw1, ffw2, x, wqkv, bqkv, h,
                                   Qpack0, KB1_0, KB2_0, VhiT0, VloT0,
                                   B3h, B3l, B4h, B4l, W1B1, W1B2, W2h, W2l);

  layer0_fused<<<256, 1024, 0, stream>>>(
      Qpack0, KB1_0, KB2_0, VhiT0, VloT0, h,
      wo, bo, ln1g, ln1b,
      W1B1, W1B2, W2h, W2l, ffb1, ffb2, ln2g, ln2b,
      wqkv + 42 * 14, bqkv + 42,
      Qpack1, KB1_1, KB2_1, VhiT1, VloT1);

  layer1_tail<<<256, 1024, 0, stream>>>(
      Qpack1, KB1_1, KB2_1, VhiT1, VloT1, h,
      wo + 196, bo + 14, ln1g + 14, ln1b + 14,
      W1B1 + (size_t)2048 * 16, W1B2 + (size_t)2048 * 16,
      W2h + (size_t)16 * FF, W2l + (size_t)16 * FF,
      ffb1 + FF, ffb2 + 14, ln2g + 14, ln2b + 14,
      fc1w, fc1b, fc2w, fc2b, x, y,
      B3h, B3l, fc3b, B4h, B4l, fc4b,
      fc5w, fc5b, out, out + NN);
}

// Round 10
// 231.217 us; speedup vs baseline: 1.2371x; 1.0047x over previous
//
#include <hip/hip_runtime.h>
#include <math.h>

#define NN 8192
#define DD 14
#define DP 16
#define FF 2048
#define HID 256
#define LN_EPS 1e-5f
#define QSCALE (1.4426950408889634f / 3.7416573867739413f)  // log2(e)/sqrt(14)

typedef short bf16x8 __attribute__((ext_vector_type(8)));
typedef float f32x4 __attribute__((ext_vector_type(4)));

#define LOAD16(dst, srcp) { \
  const float4* _p = (const float4*)(srcp); \
  float4 _a = _p[0], _b = _p[1], _c = _p[2], _d = _p[3]; \
  dst[0]=_a.x; dst[1]=_a.y; dst[2]=_a.z; dst[3]=_a.w; \
  dst[4]=_b.x; dst[5]=_b.y; dst[6]=_b.z; dst[7]=_b.w; \
  dst[8]=_c.x; dst[9]=_c.y; dst[10]=_c.z; dst[11]=_c.w; \
  dst[12]=_d.x; dst[13]=_d.y; dst[14]=_d.z; dst[15]=_d.w; }

#define STORE16(dstp, src) { \
  float4* _p = (float4*)(dstp); \
  _p[0] = make_float4(src[0], src[1], src[2], src[3]); \
  _p[1] = make_float4(src[4], src[5], src[6], src[7]); \
  _p[2] = make_float4(src[8], src[9], src[10], src[11]); \
  _p[3] = make_float4(src[12], src[13], src[14], src[15]); }

static __device__ __forceinline__ float fast_exp2(float x) {
#if __has_builtin(__builtin_amdgcn_exp2f)
  return __builtin_amdgcn_exp2f(x);
#else
  return exp2f(x);
#endif
}

static __device__ __forceinline__ unsigned short bf_hi(float x) {
  return (unsigned short)(__float_as_uint(x) >> 16);
}
static __device__ __forceinline__ float bf_hi_f(float x) {
  return __uint_as_float(__float_as_uint(x) & 0xffff0000u);
}

// ---- repack 8 floats -> bf16 hi/lo fragments ----
static __device__ __forceinline__ void split8(const float* pv, bf16x8* ph, bf16x8* pl) {
  #pragma unroll
  for (int i = 0; i < 8; i++) {
    unsigned int u = __float_as_uint(pv[i]);
    (*ph)[i] = (short)(u >> 16);
    float rr = pv[i] - __uint_as_float(u & 0xffff0000u);
    (*pl)[i] = (short)(__float_as_uint(rr) >> 16);
  }
}

// ---- shared helper: compute qkv for row r from hr[16], store packed operands ----
static __device__ __forceinline__ void qkv_compute_store(
    int r, const float* hr, const float* __restrict__ wqkv,
    const float* __restrict__ bqkv, unsigned int* __restrict__ Qpack,
    unsigned int* __restrict__ KB1, unsigned int* __restrict__ KB2,
    unsigned short* __restrict__ VhiT, unsigned short* __restrict__ VloT) {
  float q[14], k[14], v[14];
  #pragma unroll 6
  for (int c = 0; c < 42; c++) {
    const float* w = wqkv + c * 14;
    float s = bqkv[c];
    #pragma unroll
    for (int d = 0; d < 14; d++) s = fmaf(hr[d], w[d], s);
    if (c < 14)       q[c] = s * QSCALE;
    else if (c < 28)  k[c - 14] = s;
    else              v[c - 28] = s;
  }
  unsigned int qp[16], k1[16], k2[16];
  unsigned short qh[14], ql[14], kh[14], kl[14];
  #pragma unroll
  for (int d = 0; d < 14; d++) {
    qh[d] = bf_hi(q[d]);
    ql[d] = bf_hi(q[d] - bf_hi_f(q[d]));
    kh[d] = bf_hi(k[d]);
    kl[d] = bf_hi(k[d] - bf_hi_f(k[d]));
  }
  #pragma unroll
  for (int i = 0; i < 7; i++) {
    qp[i]     = (unsigned int)qh[2*i] | ((unsigned int)qh[2*i+1] << 16);
    qp[8 + i] = (unsigned int)ql[2*i] | ((unsigned int)ql[2*i+1] << 16);
    k1[i]     = (unsigned int)kh[2*i] | ((unsigned int)kh[2*i+1] << 16);
    k1[8 + i] = k1[i];
    k2[i]     = (unsigned int)kl[2*i] | ((unsigned int)kl[2*i+1] << 16);
    k2[8 + i] = k2[i];
  }
  qp[7] = 0; qp[15] = 0; k1[7] = 0; k1[15] = 0; k2[7] = 0; k2[15] = 0;
  uint4* Qp4 = (uint4*)(Qpack + (size_t)r * 16);
  uint4* K14 = (uint4*)(KB1 + (size_t)r * 16);
  uint4* K24 = (uint4*)(KB2 + (size_t)r * 16);
  #pragma unroll
  for (int i = 0; i < 4; i++) {
    Qp4[i] = make_uint4(qp[4*i], qp[4*i+1], qp[4*i+2], qp[4*i+3]);
    K14[i] = make_uint4(k1[4*i], k1[4*i+1], k1[4*i+2], k1[4*i+3]);
    K24[i] = make_uint4(k2[4*i], k2[4*i+1], k2[4*i+2], k2[4*i+3]);
  }
  #pragma unroll
  for (int d = 0; d < 14; d++) {
    VhiT[(size_t)d * NN + r] = bf_hi(v[d]);
    VloT[(size_t)d * NN + r] = bf_hi(v[d] - bf_hi_f(v[d]));
  }
  VhiT[(size_t)14 * NN + r] = 0x3F80;  // ones column = softmax denom
  VhiT[(size_t)15 * NN + r] = 0;
  VloT[(size_t)14 * NN + r] = 0;
  VloT[(size_t)15 * NN + r] = 0;
}

// ---- shared helper: A-operand pack of 14-dim vector (hi|lo) ----
static __device__ __forceinline__ void store_apack(unsigned int* dst, const float* o) {
  unsigned int qp[16];
  unsigned short hh[14], ll[14];
  #pragma unroll
  for (int d = 0; d < 14; d++) {
    hh[d] = bf_hi(o[d]);
    ll[d] = bf_hi(o[d] - bf_hi_f(o[d]));
  }
  #pragma unroll
  for (int i = 0; i < 7; i++) {
    qp[i]     = (unsigned int)hh[2*i] | ((unsigned int)hh[2*i+1] << 16);
    qp[8 + i] = (unsigned int)ll[2*i] | ((unsigned int)ll[2*i+1] << 16);
  }
  qp[7] = 0; qp[15] = 0;
  uint4* d4 = (uint4*)dst;
  #pragma unroll
  for (int i = 0; i < 4; i++)
    d4[i] = make_uint4(qp[4*i], qp[4*i+1], qp[4*i+2], qp[4*i+3]);
}

// ---- combine + LN (out-proj variant) ----
static __device__ __forceinline__ void combine_ln1(
    const float* srow, const float* hr, const float* __restrict__ wo,
    const float* __restrict__ bo, const float* __restrict__ g,
    const float* __restrict__ b, float* o) {
  float L = srow[14];
  float inv = 1.f / L;
  float a[14];
  #pragma unroll
  for (int d = 0; d < 14; d++) a[d] = srow[d] * inv;
  float xx[14];
  #pragma unroll
  for (int i = 0; i < 14; i++) {
    float s = bo[i];
    #pragma unroll
    for (int d = 0; d < 14; d++) s = fmaf(wo[i * 14 + d], a[d], s);
    xx[i] = hr[i] + s;
  }
  float mu = 0.f;
  #pragma unroll
  for (int i = 0; i < 14; i++) mu += xx[i];
  mu *= (1.f / 14.f);
  float var = 0.f;
  #pragma unroll
  for (int i = 0; i < 14; i++) { float tt = xx[i] - mu; var = fmaf(tt, tt, var); }
  var *= (1.f / 14.f);
  float rs = rsqrtf(var + LN_EPS);
  #pragma unroll
  for (int i = 0; i < 14; i++) o[i] = fmaf((xx[i] - mu) * rs, g[i], b[i]);
  o[14] = 0.f; o[15] = 0.f;
}

// ======================================================================
// K1: weight packs (fc3/fc4/ffn) + layer-0 qkv from x  (unchanged, proven)
// ======================================================================
__global__ void pack_all(const float* __restrict__ w3, const float* __restrict__ w4,
                         const float* __restrict__ ffw1, const float* __restrict__ ffw2,
                         const float* __restrict__ x, const float* __restrict__ wqkv,
                         const float* __restrict__ bqkv, float* __restrict__ h,
                         unsigned int* __restrict__ Qpack,
                         unsigned int* __restrict__ KB1, unsigned int* __restrict__ KB2,
                         unsigned short* __restrict__ VhiT, unsigned short* __restrict__ VloT,
                         unsigned short* __restrict__ B3h, unsigned short* __restrict__ B3l,
                         unsigned short* __restrict__ B4h, unsigned short* __restrict__ B4l,
                         unsigned int* __restrict__ W1B1, unsigned int* __restrict__ W1B2,
                         unsigned short* __restrict__ W2h, unsigned short* __restrict__ W2l) {
  const int blk = blockIdx.x, tid = threadIdx.x;
  if (blk < 32) {
    int t = blk * 256 + tid;
    int lane = t & 63, ks = (t >> 6) & 7, nt = t >> 9;
    int n = nt * 16 + (lane & 15);
    int k0 = ks * 32 + (lane >> 4) * 8;
    unsigned int h4[4], l4[4];
    #pragma unroll
    for (int jj = 0; jj < 4; jj++) {
      unsigned short h2[2], l2[2];
      #pragma unroll
      for (int e = 0; e < 2; e++) {
        float v = w4[(size_t)n * 256 + k0 + jj * 2 + e];
        h2[e] = bf_hi(v);
        l2[e] = bf_hi(v - bf_hi_f(v));
      }
      h4[jj] = (unsigned int)h2[0] | ((unsigned int)h2[1] << 16);
      l4[jj] = (unsigned int)l2[0] | ((unsigned int)l2[1] << 16);
    }
    ((uint4*)B4h)[t] = make_uint4(h4[0], h4[1], h4[2], h4[3]);
    ((uint4*)B4l)[t] = make_uint4(l4[0], l4[1], l4[2], l4[3]);
    if (ks < 2) {
      int fi = (nt * 2 + ks) * 64 + lane;
      #pragma unroll
      for (int jj = 0; jj < 4; jj++) {
        unsigned short h2[2], l2[2];
        #pragma unroll
        for (int e = 0; e < 2; e++) {
          int k = k0 + jj * 2 + e;
          float v = (k < 51) ? w3[(size_t)n * 51 + k] : 0.f;
          h2[e] = bf_hi(v);
          l2[e] = bf_hi(v - bf_hi_f(v));
        }
        h4[jj] = (unsigned int)h2[0] | ((unsigned int)h2[1] << 16);
        l4[jj] = (unsigned int)l2[0] | ((unsigned int)l2[1] << 16);
      }
      ((uint4*)B3h)[fi] = make_uint4(h4[0], h4[1], h4[2], h4[3]);
      ((uint4*)B3l)[fi] = make_uint4(l4[0], l4[1], l4[2], l4[3]);
    }
  } else if (blk < 48) {
    int t = (blk - 32) * 256 + tid;
    int l = t >> 11, j = t & 2047;
    const float* wrow = ffw1 + ((size_t)l * FF + j) * 14;
    unsigned int k1[16], k2[16];
    unsigned short kh[14], kl[14];
    #pragma unroll
    for (int d = 0; d < 14; d++) {
      float v = wrow[d];
      kh[d] = bf_hi(v);
      kl[d] = bf_hi(v - bf_hi_f(v));
    }
    #pragma unroll
    for (int i = 0; i < 7; i++) {
      k1[i] = (unsigned int)kh[2*i] | ((unsigned int)kh[2*i+1] << 16);
      k1[8 + i] = k1[i];
      k2[i] = (unsigned int)kl[2*i] | ((unsigned int)kl[2*i+1] << 16);
      k2[8 + i] = k2[i];
    }
    k1[7] = 0; k1[15] = 0; k2[7] = 0; k2[15] = 0;
    uint4* d1 = (uint4*)(W1B1 + (size_t)t * 16);
    uint4* d2 = (uint4*)(W1B2 + (size_t)t * 16);
    #pragma unroll
    for (int i = 0; i < 4; i++) {
      d1[i] = make_uint4(k1[4*i], k1[4*i+1], k1[4*i+2], k1[4*i+3]);
      d2[i] = make_uint4(k2[4*i], k2[4*i+1], k2[4*i+2], k2[4*i+3]);
    }
  } else if (blk < 64) {
    int t = (blk - 48) * 256 + tid;
    int l = t >> 11, j = t & 2047;
    #pragma unroll
    for (int d = 0; d < 16; d++) {
      float v = (d < 14) ? ffw2[((size_t)l * 14 + d) * FF + j] : 0.f;
      W2h[((size_t)l * 16 + d) * FF + j] = bf_hi(v);
      W2l[((size_t)l * 16 + d) * FF + j] = bf_hi(v - bf_hi_f(v));
    }
  } else {
    int r = (blk - 64) * 256 + tid;
    float hr[16];
    #pragma unroll
    for (int d = 0; d < 14; d++) hr[d] = x[(size_t)r * 14 + d];
    hr[14] = 0.f; hr[15] = 0.f;
    STORE16(h + (size_t)r * DP, hr);
    qkv_compute_store(r, hr, wqkv, bqkv, Qpack, KB1, KB2, VhiT, VloT);
  }
}

// ======================================================================
// Pipelined attention core: 32-key chunks; LDS reads of P(c-1) issued at
// the top of iter c so S-MFMA+exp hide the latency (single buffer is
// safe: per-wave DS ops execute in order).
// ======================================================================
static __device__ __forceinline__ void attn_core(
    const bf16x8* __restrict__ Qp, const bf16x8* __restrict__ B1,
    const bf16x8* __restrict__ B2, const bf16x8* __restrict__ Vh,
    const bf16x8* __restrict__ Vl, int qbase, int wave, int lo4, int hi4,
    float (*Pl)[36], f32x4* o0, f32x4* o1) {
  const f32x4 zero = {0.f, 0.f, 0.f, 0.f};
  bf16x8 aQ0 = Qp[(size_t)(qbase + lo4) * 4 + hi4];
  bf16x8 aQ1 = Qp[(size_t)(qbase + 16 + lo4) * 4 + hi4];
  f32x4 acc0 = zero, acc1 = zero;
  const int kstart = wave * 1024;
  float4 ra0, ra1, rc0, rc1;
  const float4* p0 = (const float4*)&Pl[lo4][hi4 * 8];
  const float4* p1 = (const float4*)&Pl[16 + lo4][hi4 * 8];

  for (int c = 0; c < 32; c++) {
    const int kb = kstart + c * 32;
    if (c > 0) {            // issue reads of P(c-1) early
      ra0 = p0[0]; ra1 = p0[1]; rc0 = p1[0]; rc1 = p1[1];
      __asm__ volatile("" ::: "memory");   // keep reads above the writes below
    }
    bf16x8 b1g0 = B1[(size_t)(kb + lo4) * 4 + hi4];
    bf16x8 b2g0 = B2[(size_t)(kb + lo4) * 4 + hi4];
    bf16x8 b1g1 = B1[(size_t)(kb + 16 + lo4) * 4 + hi4];
    bf16x8 b2g1 = B2[(size_t)(kb + 16 + lo4) * 4 + hi4];
    bf16x8 vh = Vh[(size_t)lo4 * 1024 + (kb >> 3) + hi4];
    bf16x8 vl = Vl[(size_t)lo4 * 1024 + (kb >> 3) + hi4];

    f32x4 s00 = __builtin_amdgcn_mfma_f32_16x16x32_bf16(aQ0, b1g0, zero, 0, 0, 0);
    f32x4 s01 = __builtin_amdgcn_mfma_f32_16x16x32_bf16(aQ0, b1g1, zero, 0, 0, 0);
    f32x4 s10 = __builtin_amdgcn_mfma_f32_16x16x32_bf16(aQ1, b1g0, zero, 0, 0, 0);
    f32x4 s11 = __builtin_amdgcn_mfma_f32_16x16x32_bf16(aQ1, b1g1, zero, 0, 0, 0);
    s00 = __builtin_amdgcn_mfma_f32_16x16x32_bf16(aQ0, b2g0, s00, 0, 0, 0);
    s01 = __builtin_amdgcn_mfma_f32_16x16x32_bf16(aQ0, b2g1, s01, 0, 0, 0);
    s10 = __builtin_amdgcn_mfma_f32_16x16x32_bf16(aQ1, b2g0, s10, 0, 0, 0);
    s11 = __builtin_amdgcn_mfma_f32_16x16x32_bf16(aQ1, b2g1, s11, 0, 0, 0);
    // write P(c) (queued after the reads -> reads return old data)
    #pragma unroll
    for (int reg = 0; reg < 4; reg++) {
      Pl[hi4 * 4 + reg][lo4]           = fast_exp2(s00[reg]);
      Pl[hi4 * 4 + reg][16 + lo4]      = fast_exp2(s01[reg]);
      Pl[16 + hi4 * 4 + reg][lo4]      = fast_exp2(s10[reg]);
      Pl[16 + hi4 * 4 + reg][16 + lo4] = fast_exp2(s11[reg]);
    }
    if (c > 0) {            // PV of chunk c-1 (V frags of c-1 kept below)
      const int kbp = kb - 32;
      bf16x8 vhp = Vh[(size_t)lo4 * 1024 + (kbp >> 3) + hi4];
      bf16x8 vlp = Vl[(size_t)lo4 * 1024 + (kbp >> 3) + hi4];
      float pv0[8] = {ra0.x, ra0.y, ra0.z, ra0.w, ra1.x, ra1.y, ra1.z, ra1.w};
      float pv1[8] = {rc0.x, rc0.y, rc0.z, rc0.w, rc1.x, rc1.y, rc1.z, rc1.w};
      bf16x8 ph0, pl0, ph1, pl1;
      split8(pv0, &ph0, &pl0);
      split8(pv1, &ph1, &pl1);
      acc0 = __builtin_amdgcn_mfma_f32_16x16x32_bf16(ph0, vhp, acc0, 0, 0, 0);
      acc1 = __builtin_amdgcn_mfma_f32_16x16x32_bf16(ph1, vhp, acc1, 0, 0, 0);
      acc0 = __builtin_amdgcn_mfma_f32_16x16x32_bf16(pl0, vhp, acc0, 0, 0, 0);
      acc1 = __builtin_amdgcn_mfma_f32_16x16x32_bf16(pl1, vhp, acc1, 0, 0, 0);
      acc0 = __builtin_amdgcn_mfma_f32_16x16x32_bf16(ph0, vlp, acc0, 0, 0, 0);
      acc1 = __builtin_amdgcn_mfma_f32_16x16x32_bf16(ph1, vlp, acc1, 0, 0, 0);
    }
  }
  // epilogue: PV of chunk 31
  {
    const int kbp = kstart + 31 * 32;
    bf16x8 vhp = Vh[(size_t)lo4 * 1024 + (kbp >> 3) + hi4];
    bf16x8 vlp = Vl[(size_t)lo4 * 1024 + (kbp >> 3) + hi4];
    float4 a0 = p0[0], a1 = p0[1], c0 = p1[0], c1 = p1[1];
    float pv0[8] = {a0.x, a0.y, a0.z, a0.w, a1.x, a1.y, a1.z, a1.w};
    float pv1[8] = {c0.x, c0.y, c0.z, c0.w, c1.x, c1.y, c1.z, c1.w};
    bf16x8 ph0, pl0, ph1, pl1;
    split8(pv0, &ph0, &pl0);
    split8(pv1, &ph1, &pl1);
    acc0 = __builtin_amdgcn_mfma_f32_16x16x32_bf16(ph0, vhp, acc0, 0, 0, 0);
    acc1 = __builtin_amdgcn_mfma_f32_16x16x32_bf16(ph1, vhp, acc1, 0, 0, 0);
    acc0 = __builtin_amdgcn_mfma_f32_16x16x32_bf16(pl0, vhp, acc0, 0, 0, 0);
    acc1 = __builtin_amdgcn_mfma_f32_16x16x32_bf16(pl1, vhp, acc1, 0, 0, 0);
    acc0 = __builtin_amdgcn_mfma_f32_16x16x32_bf16(ph0, vlp, acc0, 0, 0, 0);
    acc1 = __builtin_amdgcn_mfma_f32_16x16x32_bf16(ph1, vlp, acc1, 0, 0, 0);
  }
  *o0 = acc0; *o1 = acc1;
}

// ======================================================================
// Pipelined FFN core: 8 neuron chunks of 32, same pipeline structure.
// ======================================================================
static __device__ __forceinline__ void ffn_core(
    bf16x8 aH0, bf16x8 aH1, const bf16x8* __restrict__ B1,
    const bf16x8* __restrict__ B2, const bf16x8* __restrict__ Vh,
    const bf16x8* __restrict__ Vl, const float* __restrict__ b1,
    int jstart, int lo4, int hi4, float (*Pl)[36], f32x4* o0, f32x4* o1) {
  const f32x4 zero = {0.f, 0.f, 0.f, 0.f};
  f32x4 acc0 = zero, acc1 = zero;
  float4 ra0, ra1, rc0, rc1;
  const float4* p0 = (const float4*)&Pl[lo4][hi4 * 8];
  const float4* p1 = (const float4*)&Pl[16 + lo4][hi4 * 8];

  for (int c = 0; c < 8; c++) {
    const int jb = jstart + c * 32;
    if (c > 0) {
      ra0 = p0[0]; ra1 = p0[1]; rc0 = p1[0]; rc1 = p1[1];
      __asm__ volatile("" ::: "memory");
    }
    bf16x8 b1g0 = B1[(size_t)(jb + lo4) * 4 + hi4];
    bf16x8 b2g0 = B2[(size_t)(jb + lo4) * 4 + hi4];
    bf16x8 b1g1 = B1[(size_t)(jb + 16 + lo4) * 4 + hi4];
    bf16x8 b2g1 = B2[(size_t)(jb + 16 + lo4) * 4 + hi4];
    float bb0 = b1[jb + lo4];
    float bb1 = b1[jb + 16 + lo4];

    f32x4 s00 = __builtin_amdgcn_mfma_f32_16x16x32_bf16(aH0, b1g0, zero, 0, 0, 0);
    f32x4 s01 = __builtin_amdgcn_mfma_f32_16x16x32_bf16(aH0, b1g1, zero, 0, 0, 0);
    f32x4 s10 = __builtin_amdgcn_mfma_f32_16x16x32_bf16(aH1, b1g0, zero, 0, 0, 0);
    f32x4 s11 = __builtin_amdgcn_mfma_f32_16x16x32_bf16(aH1, b1g1, zero, 0, 0, 0);
    s00 = __builtin_amdgcn_mfma_f32_16x16x32_bf16(aH0, b2g0, s00, 0, 0, 0);
    s01 = __builtin_amdgcn_mfma_f32_16x16x32_bf16(aH0, b2g1, s01, 0, 0, 0);
    s10 = __builtin_amdgcn_mfma_f32_16x16x32_bf16(aH1, b2g0, s10, 0, 0, 0);
    s11 = __builtin_amdgcn_mfma_f32_16x16x32_bf16(aH1, b2g1, s11, 0, 0, 0);
    #pragma unroll
    for (int reg = 0; reg < 4; reg++) {
      Pl[hi4 * 4 + reg][lo4]           = fmaxf(s00[reg] + bb0, 0.f);
      Pl[hi4 * 4 + reg][16 + lo4]      = fmaxf(s01[reg] + bb1, 0.f);
      Pl[16 + hi4 * 4 + reg][lo4]      = fmaxf(s10[reg] + bb0, 0.f);
      Pl[16 + hi4 * 4 + reg][16 + lo4] = fmaxf(s11[reg] + bb1, 0.f);
    }
    if (c > 0) {
      const int jbp = jb - 32;
      bf16x8 vhp = Vh[(size_t)lo4 * 256 + (jbp >> 3) + hi4];
      bf16x8 vlp = Vl[(size_t)lo4 * 256 + (jbp >> 3) + hi4];
      float pv0[8] = {ra0.x, ra0.y, ra0.z, ra0.w, ra1.x, ra1.y, ra1.z, ra1.w};
      float pv1[8] = {rc0.x, rc0.y, rc0.z, rc0.w, rc1.x, rc1.y, rc1.z, rc1.w};
      bf16x8 th0, tl0, th1, tl1;
      split8(pv0, &th0, &tl0);
      split8(pv1, &th1, &tl1);
      acc0 = __builtin_amdgcn_mfma_f32_16x16x32_bf16(th0, vhp, acc0, 0, 0, 0);
      acc1 = __builtin_amdgcn_mfma_f32_16x16x32_bf16(th1, vhp, acc1, 0, 0, 0);
      acc0 = __builtin_amdgcn_mfma_f32_16x16x32_bf16(tl0, vhp, acc0, 0, 0, 0);
      acc1 = __builtin_amdgcn_mfma_f32_16x16x32_bf16(tl1, vhp, acc1, 0, 0, 0);
      acc0 = __builtin_amdgcn_mfma_f32_16x16x32_bf16(th0, vlp, acc0, 0, 0, 0);
      acc1 = __builtin_amdgcn_mfma_f32_16x16x32_bf16(th1, vlp, acc1, 0, 0, 0);
    }
  }
  {
    const int jbp = jstart + 7 * 32;
    bf16x8 vhp = Vh[(size_t)lo4 * 256 + (jbp >> 3) + hi4];
    bf16x8 vlp = Vl[(size_t)lo4 * 256 + (jbp >> 3) + hi4];
    float4 a0 = p0[0], a1 = p0[1], c0 = p1[0], c1 = p1[1];
    float pv0[8] = {a0.x, a0.y, a0.z, a0.w, a1.x, a1.y, a1.z, a1.w};
    float pv1[8] = {c0.x, c0.y, c0.z, c0.w, c1.x, c1.y, c1.z, c1.w};
    bf16x8 th0, tl0, th1, tl1;
    split8(pv0, &th0, &tl0);
    split8(pv1, &th1, &tl1);
    acc0 = __builtin_amdgcn_mfma_f32_16x16x32_bf16(th0, vhp, acc0, 0, 0, 0);
    acc1 = __builtin_amdgcn_mfma_f32_16x16x32_bf16(th1, vhp, acc1, 0, 0, 0);
    acc0 = __builtin_amdgcn_mfma_f32_16x16x32_bf16(tl0, vhp, acc0, 0, 0, 0);
    acc1 = __builtin_amdgcn_mfma_f32_16x16x32_bf16(tl1, vhp, acc1, 0, 0, 0);
    acc0 = __builtin_amdgcn_mfma_f32_16x16x32_bf16(th0, vlp, acc0, 0, 0, 0);
    acc1 = __builtin_amdgcn_mfma_f32_16x16x32_bf16(th1, vlp, acc1, 0, 0, 0);
  }
  *o0 = acc0; *o1 = acc1;
}

// LDS layout (bytes):
//   0      : Plds  8 x [32][36] f32   (36864)      } tail phase reuses 0..51200
//   36864  : sacc  [8][32][16] f32    (16384)
//   53248  : hrow  [32][16] f32       (2048)
//   55296  : Hl    [32][16] u32       (2048)
//   57344  : szf   [32] f32           (128)   -> total 57472
#define SMEM_BYTES 57472

// ======================================================================
// K2: layer 0 = attn + combine/LN1 (LDS) + ffn + LN2 + layer-1 qkv pack.
// Layer-1 packs go to a SEPARATE buffer set (no race with other blocks
// still reading layer-0 packs).
// ======================================================================
__global__ __launch_bounds__(512, 4) void layer0_fused(
    const unsigned int* __restrict__ Qpack, const unsigned int* __restrict__ KB1,
    const unsigned int* __restrict__ KB2, const unsigned short* __restrict__ VhiT,
    const unsigned short* __restrict__ VloT, float* __restrict__ h,
    const float* __restrict__ wo, const float* __restrict__ bo,
    const float* __restrict__ g1, const float* __restrict__ b1n,
    const unsigned int* __restrict__ W1B1, const unsigned int* __restrict__ W1B2,
    const unsigned short* __restrict__ W2h, const unsigned short* __restrict__ W2l,
    const float* __restrict__ fb1, const float* __restrict__ fb2,
    const float* __restrict__ g2, const float* __restrict__ b2n,
    const float* __restrict__ wqkv1, const float* __restrict__ bqkv1,
    unsigned int* __restrict__ Qpack1, unsigned int* __restrict__ KB1_1,
    unsigned int* __restrict__ KB2_1, unsigned short* __restrict__ VhiT1,
    unsigned short* __restrict__ VloT1) {
  __shared__ alignas(16) char smem[SMEM_BYTES];
  const int tid = threadIdx.x;
  const int wave = tid >> 6;
  const int lane = tid & 63;
  const int lo4 = lane & 15;
  const int hi4 = lane >> 4;
  const int qbase = blockIdx.x * 32;

  float (*Pl)[36] = (float(*)[36])(smem + wave * 4608);
  float (*sacc)[32][16] = (float(*)[32][16])(smem + 36864);
  float (*hrow)[16] = (float(*)[16])(smem + 53248);
  unsigned int (*Hl)[16] = (unsigned int(*)[16])(smem + 55296);

  // ---- phase A: attention ----
  f32x4 a0, a1;
  attn_core((const bf16x8*)Qpack, (const bf16x8*)KB1, (const bf16x8*)KB2,
            (const bf16x8*)VhiT, (const bf16x8*)VloT, qbase, wave, lo4, hi4,
            Pl, &a0, &a1);
  #pragma unroll
  for (int reg = 0; reg < 4; reg++) {
    sacc[wave][hi4 * 4 + reg][lo4] = a0[reg];
    sacc[wave][16 + hi4 * 4 + reg][lo4] = a1[reg];
  }
  __syncthreads();
  {
    int qq = tid >> 4, col = tid & 15;
    float v = 0.f;
    #pragma unroll
    for (int w = 0; w < 8; w++) v += sacc[w][qq][col];
    sacc[0][qq][col] = v;
  }
  __syncthreads();
  if (tid < 32) {
    int r = qbase + tid;
    float hr[16];
    LOAD16(hr, h + (size_t)r * DP);
    float o[16];
    combine_ln1(&sacc[0][tid][0], hr, wo, bo, g1, b1n, o);
    #pragma unroll
    for (int i = 0; i < 16; i++) hrow[tid][i] = o[i];
    store_apack(&Hl[tid][0], o);
  }
  __syncthreads();

  // ---- phase B: FFN ----
  bf16x8 aH0 = *(const bf16x8*)&Hl[lo4][hi4 * 4];
  bf16x8 aH1 = *(const bf16x8*)&Hl[16 + lo4][hi4 * 4];
  f32x4 f0, f1;
  ffn_core(aH0, aH1, (const bf16x8*)W1B1, (const bf16x8*)W1B2,
           (const bf16x8*)W2h, (const bf16x8*)W2l, fb1, wave * 256,
           lo4, hi4, Pl, &f0, &f1);
  __syncthreads();
  #pragma unroll
  for (int reg = 0; reg < 4; reg++) {
    sacc[wave][hi4 * 4 + reg][lo4] = f0[reg];
    sacc[wave][16 + hi4 * 4 + reg][lo4] = f1[reg];
  }
  __syncthreads();
  {
    int qq = tid >> 4, col = tid & 15;
    float v = 0.f;
    #pragma unroll
    for (int w = 0; w < 8; w++) v += sacc[w][qq][col];
    sacc[0][qq][col] = v;
  }
  __syncthreads();
  if (tid < 32) {
    int r = qbase + tid;
    float xx[14];
    #pragma unroll
    for (int i = 0; i < 14; i++) xx[i] = hrow[tid][i] + sacc[0][tid][i] + fb2[i];
    float mu = 0.f;
    #pragma unroll
    for (int i = 0; i < 14; i++) mu += xx[i];
    mu *= (1.f / 14.f);
    float var = 0.f;
    #pragma unroll
    for (int i = 0; i < 14; i++) { float tt = xx[i] - mu; var = fmaf(tt, tt, var); }
    var *= (1.f / 14.f);
    float rs = rsqrtf(var + LN_EPS);
    float o[16];
    #pragma unroll
    for (int i = 0; i < 14; i++) o[i] = fmaf((xx[i] - mu) * rs, g2[i], b2n[i]);
    o[14] = 0.f; o[15] = 0.f;
    STORE16(h + (size_t)r * DP, o);
    qkv_compute_store(r, o, wqkv1, bqkv1, Qpack1, KB1_1, KB2_1, VhiT1, VloT1);
  }
}

// ======================================================================
// K3: layer 1 = attn + LN1 + ffn + LN2 + size head + regression tail.
// 32 rows/block; tail runs as two 16-row groups (waves 0-3 / 4-7).
// ======================================================================
__global__ __launch_bounds__(512, 4) void layer1_tail(
    const unsigned int* __restrict__ Qpack, const unsigned int* __restrict__ KB1,
    const unsigned int* __restrict__ KB2, const unsigned short* __restrict__ VhiT,
    const unsigned short* __restrict__ VloT, const float* __restrict__ h,
    const float* __restrict__ wo, const float* __restrict__ bo,
    const float* __restrict__ g1, const float* __restrict__ b1n,
    const unsigned int* __restrict__ W1B1, const unsigned int* __restrict__ W1B2,
    const unsigned short* __restrict__ W2h, const unsigned short* __restrict__ W2l,
    const float* __restrict__ fb1, const float* __restrict__ fb2,
    const float* __restrict__ g2, const float* __restrict__ b2n,
    const float* __restrict__ fc1w, const float* __restrict__ fc1b,
    const float* __restrict__ fc2w, const float* __restrict__ fc2b,
    const float* __restrict__ x, const float* __restrict__ y,
    const unsigned short* __restrict__ B3h, const unsigned short* __restrict__ B3l,
    const float* __restrict__ b3,
    const unsigned short* __restrict__ B4h, const unsigned short* __restrict__ B4l,
    const float* __restrict__ b4,
    const float* __restrict__ w5, const float* __restrict__ b5,
    float* __restrict__ out, float* __restrict__ outr) {
  __shared__ alignas(16) char smem[SMEM_BYTES];
  const int tid = threadIdx.x;
  const int wave = tid >> 6;
  const int lane = tid & 63;
  const int lo4 = lane & 15;
  const int hi4 = lane >> 4;
  const int qbase = blockIdx.x * 32;
  const f32x4 zero = {0.f, 0.f, 0.f, 0.f};

  float (*Pl)[36] = (float(*)[36])(smem + wave * 4608);
  float (*sacc)[32][16] = (float(*)[32][16])(smem + 36864);
  float (*hrow)[16] = (float(*)[16])(smem + 53248);
  unsigned int (*Hl)[16] = (unsigned int(*)[16])(smem + 55296);
  float* szf = (float*)(smem + 57344);

  // ---- phase A: attention (layer 1) ----
  f32x4 a0, a1;
  attn_core((const bf16x8*)Qpack, (const bf16x8*)KB1, (const bf16x8*)KB2,
            (const bf16x8*)VhiT, (const bf16x8*)VloT, qbase, wave, lo4, hi4,
            Pl, &a0, &a1);
  #pragma unroll
  for (int reg = 0; reg < 4; reg++) {
    sacc[wave][hi4 * 4 + reg][lo4] = a0[reg];
    sacc[wave][16 + hi4 * 4 + reg][lo4] = a1[reg];
  }
  __syncthreads();
  {
    int qq = tid >> 4, col = tid & 15;
    float v = 0.f;
    #pragma unroll
    for (int w = 0; w < 8; w++) v += sacc[w][qq][col];
    sacc[0][qq][col] = v;
  }
  __syncthreads();
  if (tid < 32) {
    int r = qbase + tid;
    float hr[16];
    LOAD16(hr, h + (size_t)r * DP);
    float o[16];
    combine_ln1(&sacc[0][tid][0], hr, wo, bo, g1, b1n, o);
    #pragma unroll
    for (int i = 0; i < 16; i++) hrow[tid][i] = o[i];
    store_apack(&Hl[tid][0], o);
  }
  __syncthreads();

  // ---- phase B: FFN (layer 1) + LN2 + size head ----
  bf16x8 aH0 = *(const bf16x8*)&Hl[lo4][hi4 * 4];
  bf16x8 aH1 = *(const bf16x8*)&Hl[16 + lo4][hi4 * 4];
  f32x4 f0, f1;
  ffn_core(aH0, aH1, (const bf16x8*)W1B1, (const bf16x8*)W1B2,
           (const bf16x8*)W2h, (const bf16x8*)W2l, fb1, wave * 256,
           lo4, hi4, Pl, &f0, &f1);
  __syncthreads();
  #pragma unroll
  for (int reg = 0; reg < 4; reg++) {
    sacc[wave][hi4 * 4 + reg][lo4] = f0[reg];
    sacc[wave][16 + hi4 * 4 + reg][lo4] = f1[reg];
  }
  __syncthreads();
  {
    int qq = tid >> 4, col = tid & 15;
    float v = 0.f;
    #pragma unroll
    for (int w = 0; w < 8; w++) v += sacc[w][qq][col];
    sacc[0][qq][col] = v;
  }
  __syncthreads();
  if (tid < 32) {
    int r = qbase + tid;
    float xx[14];
    #pragma unroll
    for (int i = 0; i < 14; i++) xx[i] = hrow[tid][i] + sacc[0][tid][i] + fb2[i];
    float mu = 0.f;
    #pragma unroll
    for (int i = 0; i < 14; i++) mu += xx[i];
    mu *= (1.f / 14.f);
    float var = 0.f;
    #pragma unroll
    for (int i = 0; i < 14; i++) { float tt = xx[i] - mu; var = fmaf(tt, tt, var); }
    var *= (1.f / 14.f);
    float rs = rsqrtf(var + LN_EPS);
    float o[14];
    #pragma unroll
    for (int i = 0; i < 14; i++) o[i] = fmaf((xx[i] - mu) * rs, g2[i], b2n[i]);
    float s = fc2b[0];
    #pragma unroll
    for (int i = 0; i < 14; i++) {
      float tt = fc1b[i];
      #pragma unroll
      for (int d = 0; d < 14; d++) tt = fmaf(fc1w[i * 14 + d], o[d], tt);
      s = fmaf(tt, fc2w[i], s);
    }
    out[r] = s;
    int si = (int)s;  // trunc toward zero, matches astype(int32)
    szf[tid] = (float)si;
  }
  __syncthreads();

  // ---- phase C: regression head, two 16-row groups ----
  const int grp = wave >> 2;   // 0 or 1: rows [qbase+grp*16, +16)
  const int wg  = wave & 3;    // wave-in-group

  for (int idx = tid; idx < 2 * 16 * 64; idx += 512) {
    int g = idx >> 10, m = (idx >> 6) & 15, k = idx & 63;
    int r = qbase + g * 16 + m;
    float v = 0.f;
    if (k == 0)       v = szf[g * 16 + m];
    else if (k < 15)  v = x[(size_t)r * 14 + (k - 1)];
    else if (k < 51)  v = y[(size_t)r * 36 + (k - 15)];
    ((unsigned short(*)[72])(smem + g * 2304))[m][k] = bf_hi(v);
    ((unsigned short(*)[72])(smem + 4608 + g * 2304))[m][k] = bf_hi(v - bf_hi_f(v));
  }
  __syncthreads();

  unsigned short (*Ah)[72]  = (unsigned short(*)[72])(smem + grp * 2304);
  unsigned short (*Al)[72]  = (unsigned short(*)[72])(smem + 4608 + grp * 2304);
  unsigned short (*R1h)[264] = (unsigned short(*)[264])(smem + 9216 + grp * 8448);
  unsigned short (*R1l)[264] = (unsigned short(*)[264])(smem + 26112 + grp * 8448);
  float (*sred)[16][16] = (float(*)[16][16])(smem + 43008 + (size_t)grp * 4096);

  f32x4 acc[4];
  #pragma unroll
  for (int nt = 0; nt < 4; nt++) acc[nt] = zero;
  #pragma unroll
  for (int ks = 0; ks < 2; ks++) {
    bf16x8 ah = *(const bf16x8*)&Ah[lo4][ks * 32 + hi4 * 8];
    bf16x8 al = *(const bf16x8*)&Al[lo4][ks * 32 + hi4 * 8];
    #pragma unroll
    for (int nt = 0; nt < 4; nt++) {
      int fi = ((wg * 4 + nt) * 2 + ks) * 64 + lane;
      bf16x8 bh = ((const bf16x8*)B3h)[fi];
      bf16x8 bl = ((const bf16x8*)B3l)[fi];
      acc[nt] = __builtin_amdgcn_mfma_f32_16x16x32_bf16(ah, bh, acc[nt], 0, 0, 0);
      acc[nt] = __builtin_amdgcn_mfma_f32_16x16x32_bf16(al, bh, acc[nt], 0, 0, 0);
      acc[nt] = __builtin_amdgcn_mfma_f32_16x16x32_bf16(ah, bl, acc[nt], 0, 0, 0);
    }
  }
  #pragma unroll
  for (int nt = 0; nt < 4; nt++) {
    int n = (wg * 4 + nt) * 16 + lo4;
    float bbv = b3[n];
    #pragma unroll
    for (int reg = 0; reg < 4; reg++) {
      int m = hi4 * 4 + reg;
      float v = fmaxf(acc[nt][reg] + bbv, 0.f);
      R1h[m][n] = bf_hi(v);
      R1l[m][n] = bf_hi(v - bf_hi_f(v));
    }
  }
  __syncthreads();

  #pragma unroll
  for (int nt = 0; nt < 4; nt++) acc[nt] = zero;
  #pragma unroll
  for (int ks = 0; ks < 8; ks++) {
    bf16x8 ah = *(const bf16x8*)&R1h[lo4][ks * 32 + hi4 * 8];
    bf16x8 al = *(const bf16x8*)&R1l[lo4][ks * 32 + hi4 * 8];
    #pragma unroll
    for (int nt = 0; nt < 4; nt++) {
      int fi = ((wg * 4 + nt) * 8 + ks) * 64 + lane;
      bf16x8 bh = ((const bf16x8*)B4h)[fi];
      bf16x8 bl = ((const bf16x8*)B4l)[fi];
      acc[nt] = __builtin_amdgcn_mfma_f32_16x16x32_bf16(ah, bh, acc[nt], 0, 0, 0);
      acc[nt] = __builtin_amdgcn_mfma_f32_16x16x32_bf16(al, bh, acc[nt], 0, 0, 0);
      acc[nt] = __builtin_amdgcn_mfma_f32_16x16x32_bf16(ah, bl, acc[nt], 0, 0, 0);
    }
  }
  float s4[4] = {0.f, 0.f, 0.f, 0.f};
  #pragma unroll
  for (int nt = 0; nt < 4; nt++) {
    int n = (wg * 4 + nt) * 16 + lo4;
    float bbv = b4[n], ww = w5[n];
    #pragma unroll
    for (int reg = 0; reg < 4; reg++)
      s4[reg] = fmaf(fmaxf(acc[nt][reg] + bbv, 0.f), ww, s4[reg]);
  }
  #pragma unroll
  for (int reg = 0; reg < 4; reg++) sred[wg][hi4 * 4 + reg][lo4] = s4[reg];
  __syncthreads();

  if (tid < 32) {
    int g = tid >> 4, m = tid & 15;
    float (*sredG)[16][16] = (float(*)[16][16])(smem + 43008 + (size_t)g * 4096);
    float t = b5[0];
    #pragma unroll
    for (int w = 0; w < 4; w++) {
      const float4* p = (const float4*)&sredG[w][m][0];
      float4 q0 = p[0], q1 = p[1], q2 = p[2], q3 = p[3];
      t += ((q0.x + q0.y) + (q0.z + q0.w)) + ((q1.x + q1.y) + (q1.z + q1.w)) +
           ((q2.x + q2.y) + (q2.z + q2.w)) + ((q3.x + q3.y) + (q3.z + q3.w));
    }
    float sz = szf[tid];
    outr[qbase + tid] = (sz != 0.f) ? t : 0.f;
  }
}

extern "C" void kernel_launch(void* const* d_in, const int* in_sizes, int n_in,
                              void* d_out, int out_size, void* d_ws, size_t ws_size,
                              hipStream_t stream) {
  const float* x    = (const float*)d_in[0];
  const float* y    = (const float*)d_in[1];
  const float* wqkv = (const float*)d_in[2];
  const float* bqkv = (const float*)d_in[3];
  const float* wo   = (const float*)d_in[4];
  const float* bo   = (const float*)d_in[5];
  const float* ln1g = (const float*)d_in[6];
  const float* ln1b = (const float*)d_in[7];
  const float* ffw1 = (const float*)d_in[8];
  const float* ffb1 = (const float*)d_in[9];
  const float* ffw2 = (const float*)d_in[10];
  const float* ffb2 = (const float*)d_in[11];
  const float* ln2g = (const float*)d_in[12];
  const float* ln2b = (const float*)d_in[13];
  const float* fc1w = (const float*)d_in[14];
  const float* fc1b = (const float*)d_in[15];
  const float* fc2w = (const float*)d_in[16];
  const float* fc2b = (const float*)d_in[17];
  const float* fc3w = (const float*)d_in[18];
  const float* fc3b = (const float*)d_in[19];
  const float* fc4w = (const float*)d_in[20];
  const float* fc4b = (const float*)d_in[21];
  const float* fc5w = (const float*)d_in[22];
  const float* fc5b = (const float*)d_in[23];

  float* ws = (float*)d_ws;
  float*          h      = ws;                               // 131072 f
  unsigned int*   Qpack0 = (unsigned int*)(ws + 131072);
  unsigned int*   KB1_0  = (unsigned int*)(ws + 262144);
  unsigned int*   KB2_0  = (unsigned int*)(ws + 393216);
  unsigned short* VhiT0  = (unsigned short*)(ws + 524288);
  unsigned short* VloT0  = (unsigned short*)(ws + 589824);
  // layer-1 packs in the old 'part' region (no longer used)
  unsigned int*   Qpack1 = (unsigned int*)(ws + 786432);
  unsigned int*   KB1_1  = (unsigned int*)(ws + 917504);
  unsigned int*   KB2_1  = (unsigned int*)(ws + 1048576);
  unsigned short* VhiT1  = (unsigned short*)(ws + 1179648);
  unsigned short* VloT1  = (unsigned short*)(ws + 1245184);
  unsigned short* B3h    = (unsigned short*)(ws + 2891776);
  unsigned short* B3l    = (unsigned short*)(ws + 2899968);
  unsigned short* B4h    = (unsigned short*)(ws + 2908160);
  unsigned short* B4l    = (unsigned short*)(ws + 2940928);
  unsigned int*   W1B1   = (unsigned int*)(ws + 2973696);
  unsigned int*   W1B2   = (unsigned int*)(ws + 3039232);
  unsigned short* W2h    = (unsigned short*)(ws + 3104768);
  unsigned short* W2l    = (unsigned short*)(ws + 3137536);

  float* out = (float*)d_out;

  pack_all<<<96, 256, 0, stream>>>(fc3w, fc4w, ffw1, ffw2, x, wqkv, bqkv, h,
                                   Qpack0, KB1_0, KB2_0, VhiT0, VloT0,
                                   B3h, B3l, B4h, B4l, W1B1, W1B2, W2h, W2l);

  layer0_fused<<<256, 512, 0, stream>>>(
      Qpack0, KB1_0, KB2_0, VhiT0, VloT0, h,
      wo, bo, ln1g, ln1b,
      W1B1, W1B2, W2h, W2l, ffb1, ffb2, ln2g, ln2b,
      wqkv + 42 * 14, bqkv + 42,
      Qpack1, KB1_1, KB2_1, VhiT1, VloT1);

  layer1_tail<<<256, 512, 0, stream>>>(
      Qpack1, KB1_1, KB2_1, VhiT1, VloT1, h,
      wo + 196, bo + 14, ln1g + 14, ln1b + 14,
      W1B1 + (size_t)2048 * 16, W1B2 + (size_t)2048 * 16,
      W2h + (size_t)16 * FF, W2l + (size_t)16 * FF,
      ffb1 + FF, ffb2 + 14, ln2g + 14, ln2b + 14,
      fc1w, fc1b, fc2w, fc2b, x, y,
      B3h, B3l, fc3b, B4h, B4l, fc4b,
      fc5w, fc5b, out, out + NN);
}